// Round 5
// baseline (584.519 us; speedup 1.0000x reference)
//
#include <hip/hip_runtime.h>

#define NN 10000
#define NE 640000
#define D 128
#define NF (NN * D)

// ---------------- CSR build ----------------

__global__ void zero_cnt_kernel(int* __restrict__ cnt) {
    int i = blockIdx.x * 256 + threadIdx.x;
    if (i < NN) cnt[i] = 0;
}

__global__ void hist_kernel(const int* __restrict__ ei, int* __restrict__ cnt) {
    int e = blockIdx.x * 256 + threadIdx.x;
    if (e < NE) atomicAdd(&cnt[ei[NE + e]], 1);
}

__global__ void scan_kernel(const int* __restrict__ cnt, int* __restrict__ row_ptr,
                            int* __restrict__ cursor) {
    __shared__ int lds[256];
    int t = threadIdx.x;
    const int CH = (NN + 255) / 256;  // 40
    int base = t * CH;
    int s = 0;
    for (int i = 0; i < CH; i++) {
        int idx = base + i;
        if (idx < NN) s += cnt[idx];
    }
    lds[t] = s;
    __syncthreads();
    for (int off = 1; off < 256; off <<= 1) {
        int v = (t >= off) ? lds[t - off] : 0;
        __syncthreads();
        lds[t] += v;
        __syncthreads();
    }
    int run = (t == 0) ? 0 : lds[t - 1];
    for (int i = 0; i < CH; i++) {
        int idx = base + i;
        if (idx < NN) {
            row_ptr[idx] = run;
            cursor[idx] = run;
            run += cnt[idx];
        }
    }
    if (t == 255) row_ptr[NN] = lds[255];
}

// meta[pos] = {src as int-bits, edge weight} — one 8B record per edge
__global__ void scatter_kernel(const int* __restrict__ ei, const float* __restrict__ conf,
                               int* __restrict__ cursor, float2* __restrict__ meta) {
    int e = blockIdx.x * 256 + threadIdx.x;
    if (e >= NE) return;
    int s = ei[e];
    int d = ei[NE + e];
    int pos = atomicAdd(&cursor[d], 1);
    meta[pos] = make_float2(__int_as_float(s), expf(-fabsf(conf[s] - conf[d])));
}

// ---------------- fused 2-layer MLP: C = (relu(A@W1+b1))@W2 + b2 ----------------
// ONE WAVE PER BLOCK (64 threads), 16 rows per wave, fully independent — no
// barriers, no cross-wave sharing. Grid 625 x 2 problems = 1250 blocks.
// Lane owns adjacent output cols (2*lane, 2*lane+1) -> all global accesses are
// coalesced float2/float4, and outputs are CANONICAL layout.
// Wave-private 8 KiB LDS holds the A tile, then is overwritten by the T tile
// (only this wave touches it; per-wave DS ordering makes that safe).
// NN = 625*16 exactly -> no bounds checks.

__global__ __launch_bounds__(64) void mlp_pair_kernel(
    const float* __restrict__ A,
    const float* __restrict__ W1a, const float* __restrict__ b1a,
    const float* __restrict__ W2a, const float* __restrict__ b2a, float* __restrict__ Ca,
    const float* __restrict__ W1b, const float* __restrict__ b1b,
    const float* __restrict__ W2b, const float* __restrict__ b2b, float* __restrict__ Cb) {
    const float* W1 = blockIdx.y ? W1b : W1a;
    const float* b1 = blockIdx.y ? b1b : b1a;
    const float* W2 = blockIdx.y ? W2b : W2a;
    const float* b2 = blockIdx.y ? b2b : b2a;
    float* C = blockIdx.y ? Cb : Ca;

    __shared__ float Sl[16][D];   // 8 KiB: A tile, then T tile
    int lane = threadIdx.x;       // 0..63
    int row0 = blockIdx.x * 16;

    {   // stage A tile: 2048 floats = 512 float4, 8 per lane, coalesced
        const float4* src = (const float4*)(A + (size_t)row0 * D);
        float4* dst = (float4*)&Sl[0][0];
#pragma unroll
        for (int i = 0; i < 8; i++) dst[lane + 64 * i] = src[lane + 64 * i];
    }
    __syncthreads();  // single wave: just a waitcnt

    // ---- stage 1 ----
    float acc[16][2];
#pragma unroll
    for (int r = 0; r < 16; r++) { acc[r][0] = 0.f; acc[r][1] = 0.f; }
#pragma unroll 2
    for (int k = 0; k < D; k += 4) {
        float2 w[4];
#pragma unroll
        for (int kk = 0; kk < 4; kk++) w[kk] = *(const float2*)&W1[(k + kk) * D + 2 * lane];
#pragma unroll
        for (int r = 0; r < 16; r++) {
            float4 a = *(const float4*)&Sl[r][k];   // uniform addr -> LDS broadcast
            acc[r][0] = fmaf(a.x, w[0].x, fmaf(a.y, w[1].x, fmaf(a.z, w[2].x, fmaf(a.w, w[3].x, acc[r][0]))));
            acc[r][1] = fmaf(a.x, w[0].y, fmaf(a.y, w[1].y, fmaf(a.z, w[2].y, fmaf(a.w, w[3].y, acc[r][1]))));
        }
    }
    float2 b1v = *(const float2*)&b1[2 * lane];
#pragma unroll
    for (int r = 0; r < 16; r++)   // overwrite A tile with T (wave-private, DS in-order)
        *(float2*)&Sl[r][2 * lane] =
            make_float2(fmaxf(acc[r][0] + b1v.x, 0.f), fmaxf(acc[r][1] + b1v.y, 0.f));

    // ---- stage 2 ----
    float d[16][2];
#pragma unroll
    for (int r = 0; r < 16; r++) { d[r][0] = 0.f; d[r][1] = 0.f; }
#pragma unroll 2
    for (int k = 0; k < D; k += 4) {
        float2 w[4];
#pragma unroll
        for (int kk = 0; kk < 4; kk++) w[kk] = *(const float2*)&W2[(k + kk) * D + 2 * lane];
#pragma unroll
        for (int r = 0; r < 16; r++) {
            float4 a = *(const float4*)&Sl[r][k];
            d[r][0] = fmaf(a.x, w[0].x, fmaf(a.y, w[1].x, fmaf(a.z, w[2].x, fmaf(a.w, w[3].x, d[r][0]))));
            d[r][1] = fmaf(a.x, w[0].y, fmaf(a.y, w[1].y, fmaf(a.z, w[2].y, fmaf(a.w, w[3].y, d[r][1]))));
        }
    }
    float2 b2v = *(const float2*)&b2[2 * lane];
#pragma unroll
    for (int r = 0; r < 16; r++)
        *(float2*)&C[(size_t)(row0 + r) * D + 2 * lane] =
            make_float2(d[r][0] + b2v.x, d[r][1] + b2v.y);   // canonical cols (2l, 2l+1)
}

// ---------------- CSR aggregate: one WAVE per dst node, x8 unrolled gathers ----------------
// 4 nodes per 256-thread block; 2500 blocks. 8 independent 512B row-gathers in
// flight per wave; ~32 resident waves/CU -> deep MLP latency hiding.

__global__ __launch_bounds__(256) void aggregate_kernel(
    const float2* __restrict__ Mmsg2, const float2* __restrict__ Mself2,
    const int* __restrict__ row_ptr, const float2* __restrict__ meta,
    float2* __restrict__ out2) {
    int wid = (blockIdx.x * 256 + threadIdx.x) >> 6;   // node id (2500*4 = NN exactly)
    int lane = threadIdx.x & 63;
    int beg = row_ptr[wid], end = row_ptr[wid + 1];
    float a0[8], a1[8];
#pragma unroll
    for (int u = 0; u < 8; u++) { a0[u] = 0.f; a1[u] = 0.f; }
    for (int j = beg; j < end; j += 8) {
        float2 m[8];
#pragma unroll
        for (int u = 0; u < 8; u++) {
            int jj = j + u;
            m[u] = (jj < end) ? meta[jj] : make_float2(__int_as_float(0), 0.f);
        }
        float2 g[8];
#pragma unroll
        for (int u = 0; u < 8; u++)
            g[u] = Mmsg2[(size_t)__float_as_int(m[u].x) * 64 + lane];  // 512 B/wave each
#pragma unroll
        for (int u = 0; u < 8; u++) {
            a0[u] = fmaf(m[u].y, g[u].x, a0[u]);
            a1[u] = fmaf(m[u].y, g[u].y, a1[u]);
        }
    }
    float s0 = ((a0[0] + a0[1]) + (a0[2] + a0[3])) + ((a0[4] + a0[5]) + (a0[6] + a0[7]));
    float s1 = ((a1[0] + a1[1]) + (a1[2] + a1[3])) + ((a1[4] + a1[5]) + (a1[6] + a1[7]));
    float2 sv = Mself2[(size_t)wid * 64 + lane];
    out2[(size_t)wid * 64 + lane] =
        make_float2(fmaxf(s0 + sv.x, 0.f), fmaxf(s1 + sv.y, 0.f));  // canonical
}

// ---------------- fused scoring + softmax + weighted sum ----------------
// One wave per 8 rows, 1250 independent single-wave blocks, no barriers.
// score = relu(row@W1+b1) . w2 + b2 computed fully in-register (butterfly
// reduce), then per-row softmax over the 3 layers and the weighted sum.

__global__ __launch_bounds__(64) void score_finalize_kernel(
    const float* __restrict__ st, const float* __restrict__ W1,
    const float* __restrict__ b1, const float* __restrict__ w2,
    const float* __restrict__ b2, float* __restrict__ out, float* __restrict__ lw_out) {
    __shared__ float Sl[3][8][D];   // 12 KiB, wave-private
    int lane = threadIdx.x;
    int row0 = blockIdx.x * 8;      // 1250*8 = NN exactly
    for (int l = 0; l < 3; l++) {
        const float4* src = (const float4*)(st + (size_t)l * NF + (size_t)row0 * D);
        float4* dst = (float4*)&Sl[l][0][0];
#pragma unroll
        for (int i = 0; i < 4; i++) dst[lane + 64 * i] = src[lane + 64 * i];
    }
    __syncthreads();

    float2 w2v = *(const float2*)&w2[2 * lane];
    float2 b1v = *(const float2*)&b1[2 * lane];
    float bb = b2[0];
    float sc[3][8];

    for (int l = 0; l < 3; l++) {
        float acc[8][2];
#pragma unroll
        for (int r = 0; r < 8; r++) { acc[r][0] = 0.f; acc[r][1] = 0.f; }
#pragma unroll 2
        for (int k = 0; k < D; k += 4) {
            float2 w[4];
#pragma unroll
            for (int kk = 0; kk < 4; kk++) w[kk] = *(const float2*)&W1[(k + kk) * D + 2 * lane];
#pragma unroll
            for (int r = 0; r < 8; r++) {
                float4 a = *(const float4*)&Sl[l][r][k];
                acc[r][0] = fmaf(a.x, w[0].x, fmaf(a.y, w[1].x, fmaf(a.z, w[2].x, fmaf(a.w, w[3].x, acc[r][0]))));
                acc[r][1] = fmaf(a.x, w[0].y, fmaf(a.y, w[1].y, fmaf(a.z, w[2].y, fmaf(a.w, w[3].y, acc[r][1]))));
            }
        }
#pragma unroll
        for (int r = 0; r < 8; r++) {
            float p = fmaxf(acc[r][0] + b1v.x, 0.f) * w2v.x +
                      fmaxf(acc[r][1] + b1v.y, 0.f) * w2v.y;
#pragma unroll
            for (int off = 1; off < 64; off <<= 1) p += __shfl_xor(p, off);
            sc[l][r] = p + bb;   // all lanes hold the row score
        }
    }

#pragma unroll
    for (int r = 0; r < 8; r++) {
        float s0 = sc[0][r], s1 = sc[1][r], s2 = sc[2][r];
        float m = fmaxf(s0, fmaxf(s1, s2));
        float e0 = expf(s0 - m), e1 = expf(s1 - m), e2 = expf(s2 - m);
        float inv = 1.f / (e0 + e1 + e2);
        float wl0 = e0 * inv, wl1 = e1 * inv, wl2 = e2 * inv;
        float2 v0 = *(const float2*)&Sl[0][r][2 * lane];
        float2 v1 = *(const float2*)&Sl[1][r][2 * lane];
        float2 v2 = *(const float2*)&Sl[2][r][2 * lane];
        *(float2*)&out[(size_t)(row0 + r) * D + 2 * lane] =
            make_float2(wl0 * v0.x + wl1 * v1.x + wl2 * v2.x,
                        wl0 * v0.y + wl1 * v1.y + wl2 * v2.y);
        if (lane == 0) {
            lw_out[row0 + r] = wl0;
            lw_out[NN + row0 + r] = wl1;
            lw_out[2 * NN + row0 + r] = wl2;
        }
    }
}

extern "C" void kernel_launch(void* const* d_in, const int* in_sizes, int n_in,
                              void* d_out, int out_size, void* d_ws, size_t ws_size,
                              hipStream_t stream) {
    const float* x = (const float*)d_in[0];
    const int* ei = (const int*)d_in[1];
    const float* conf = (const float*)d_in[2];
    const float* msg_W1 = (const float*)d_in[3];
    const float* msg_b1 = (const float*)d_in[4];
    const float* msg_W2 = (const float*)d_in[5];
    const float* msg_b2 = (const float*)d_in[6];
    const float* self_W1 = (const float*)d_in[7];
    const float* self_b1 = (const float*)d_in[8];
    const float* self_W2 = (const float*)d_in[9];
    const float* self_b2 = (const float*)d_in[10];
    const float* score_W1 = (const float*)d_in[11];
    const float* score_b1 = (const float*)d_in[12];
    const float* score_W2 = (const float*)d_in[13];
    const float* score_b2 = (const float*)d_in[14];

    float* out = (float*)d_out;                 // [NN,D]
    float* out_stacked = out + NF;              // [3,NN,D]  (canonical, graded)
    float* out_lw = out + 4 * (size_t)NF;       // [3,NN]

    float* w = (float*)d_ws;
    float* Mmsg = w;                            // NF (canonical)
    float* Mself = w + 1 * (size_t)NF;          // NF (canonical)
    float2* meta = (float2*)(w + 2 * (size_t)NF);  // NE x {src, weight}
    int* row_ptr = (int*)(meta + NE);           // NN+1
    int* cnt = row_ptr + NN + 1;                // NN
    int* cursor = cnt + NN;                     // NN

    const int GE = (NE + 255) / 256;            // 2500
    const int GN = (NN + 255) / 256;            // 40

    zero_cnt_kernel<<<GN, 256, 0, stream>>>(cnt);
    hist_kernel<<<GE, 256, 0, stream>>>(ei, cnt);
    scan_kernel<<<1, 256, 0, stream>>>(cnt, row_ptr, cursor);
    scatter_kernel<<<GE, 256, 0, stream>>>(ei, conf, cursor, meta);

    for (int l = 0; l < 3; l++) {
        const float* h_in = (l == 0) ? x : out_stacked + (size_t)(l - 1) * NF;
        mlp_pair_kernel<<<dim3(NN / 16, 2), 64, 0, stream>>>(
            h_in,
            msg_W1 + (size_t)l * D * D, msg_b1 + (size_t)l * D,
            msg_W2 + (size_t)l * D * D, msg_b2 + (size_t)l * D, Mmsg,
            self_W1 + (size_t)l * D * D, self_b1 + (size_t)l * D,
            self_W2 + (size_t)l * D * D, self_b2 + (size_t)l * D, Mself);
        aggregate_kernel<<<NN / 4, 256, 0, stream>>>(
            (const float2*)Mmsg, (const float2*)Mself, row_ptr, meta,
            (float2*)(out_stacked + (size_t)l * NF));
    }

    score_finalize_kernel<<<NN / 8, 64, 0, stream>>>(out_stacked, score_W1, score_b1,
                                                     score_W2, score_b2, out, out_lw);
}

// Round 6
// 472.804 us; speedup vs baseline: 1.2363x; 1.2363x over previous
//
#include <hip/hip_runtime.h>

#define NN 10000
#define NE 640000
#define D 128
#define NF (NN * D)
#define WS 136   // padded bf16 row stride: 272 B = 16B-aligned, 2-way-free LDS banks

typedef __bf16 bf16x8 __attribute__((ext_vector_type(8)));
typedef __bf16 bf16x2 __attribute__((ext_vector_type(2)));
typedef float f32x4 __attribute__((ext_vector_type(4)));

// ---------------- CSR build ----------------

__global__ void zero_cnt_kernel(int* __restrict__ cnt) {
    int i = blockIdx.x * 256 + threadIdx.x;
    if (i < NN) cnt[i] = 0;
}

__global__ void hist_kernel(const int* __restrict__ ei, int* __restrict__ cnt) {
    int e = blockIdx.x * 256 + threadIdx.x;
    if (e < NE) atomicAdd(&cnt[ei[NE + e]], 1);
}

__global__ void scan_kernel(const int* __restrict__ cnt, int* __restrict__ row_ptr,
                            int* __restrict__ cursor) {
    __shared__ int lds[256];
    int t = threadIdx.x;
    const int CH = (NN + 255) / 256;  // 40
    int base = t * CH;
    int s = 0;
    for (int i = 0; i < CH; i++) {
        int idx = base + i;
        if (idx < NN) s += cnt[idx];
    }
    lds[t] = s;
    __syncthreads();
    for (int off = 1; off < 256; off <<= 1) {
        int v = (t >= off) ? lds[t - off] : 0;
        __syncthreads();
        lds[t] += v;
        __syncthreads();
    }
    int run = (t == 0) ? 0 : lds[t - 1];
    for (int i = 0; i < CH; i++) {
        int idx = base + i;
        if (idx < NN) {
            row_ptr[idx] = run;
            cursor[idx] = run;
            run += cnt[idx];
        }
    }
    if (t == 255) row_ptr[NN] = lds[255];
}

__global__ void scatter_kernel(const int* __restrict__ ei, const float* __restrict__ conf,
                               int* __restrict__ cursor, float2* __restrict__ meta) {
    int e = blockIdx.x * 256 + threadIdx.x;
    if (e >= NE) return;
    int s = ei[e];
    int d = ei[NE + e];
    int pos = atomicAdd(&cursor[d], 1);
    meta[pos] = make_float2(__int_as_float(s), expf(-fabsf(conf[s] - conf[d])));
}

// ---------------- prep: x -> bf16, W -> bf16 transposed (Wt[n][k], stride WS) ----------------

__global__ void cvt_x_kernel(const float2* __restrict__ x2, bf16x2* __restrict__ xbf) {
    int i = blockIdx.x * 256 + threadIdx.x;  // NF/2 = 640000
    float2 v = x2[i];
    bf16x2 o;
    o.x = (__bf16)v.x;
    o.y = (__bf16)v.y;
    xbf[i] = o;
}

// mats: 0-2 msg_W1[l], 3-5 msg_W2[l], 6-8 self_W1[l], 9-11 self_W2[l], 12 score_W1
__global__ __launch_bounds__(256) void prep_wt_kernel(
    const float* __restrict__ mW1, const float* __restrict__ mW2,
    const float* __restrict__ sW1, const float* __restrict__ sW2,
    const float* __restrict__ scW1, __bf16* __restrict__ wt) {
    int m = blockIdx.x;
    const float* W = (m < 3)   ? mW1 + (size_t)m * D * D
                   : (m < 6)   ? mW2 + (size_t)(m - 3) * D * D
                   : (m < 9)   ? sW1 + (size_t)(m - 6) * D * D
                   : (m < 12)  ? sW2 + (size_t)(m - 9) * D * D
                               : scW1;
    __bf16* o = wt + (size_t)m * D * WS;
    for (int i = threadIdx.x; i < D * D; i += 256) {
        int k = i >> 7, n = i & 127;        // coalesced read, scattered u16 write
        o[n * WS + k] = (__bf16)W[i];
    }
}

// ---------------- fused 2-layer MLP via bf16 MFMA ----------------
// C = (relu(A@W1+b1))@W2 + b2, f32 output canonical. Block = 4 waves x 16 rows.
// W^T staged in LDS (W1 then W2 through the same buffer). Per-wave T tile in LDS.
// MFMA 16x16x32: A-frag A[m=lane&15][k=q*8+j]; B-frag B[k=q*8+j][n=lane&15]
// (contiguous k from Wt[n][k]); C/D col=lane&15, row=q*4+reg  [m89/m91 verified].

__global__ __launch_bounds__(256) void mlp_pair_mfma(
    const __bf16* __restrict__ Abf,
    const __bf16* __restrict__ Wt1a, const float* __restrict__ b1a,
    const __bf16* __restrict__ Wt2a, const float* __restrict__ b2a, float* __restrict__ Ca,
    const __bf16* __restrict__ Wt1b, const float* __restrict__ b1b,
    const __bf16* __restrict__ Wt2b, const float* __restrict__ b2b, float* __restrict__ Cb) {
    const __bf16* Wt1 = blockIdx.y ? Wt1b : Wt1a;
    const float* b1 = blockIdx.y ? b1b : b1a;
    const __bf16* Wt2 = blockIdx.y ? Wt2b : Wt2a;
    const float* b2 = blockIdx.y ? b2b : b2a;
    float* C = blockIdx.y ? Cb : Ca;

    __shared__ __align__(16) __bf16 Wl[D * WS];       // 34816 B: W1^T, then W2^T
    __shared__ __align__(16) __bf16 Tl[4][16 * WS];   // 4352 B per wave
    int t = threadIdx.x;
    int wid = t >> 6, lane = t & 63;
    int m16 = lane & 15, q = lane >> 4;

    {   // stage W1^T: 2176 uint4, coalesced
        const uint4* src = (const uint4*)Wt1;
        uint4* dst = (uint4*)Wl;
        for (int i = t; i < D * WS / 8; i += 256) dst[i] = src[i];
    }
    __syncthreads();

    int row0 = blockIdx.x * 64 + wid * 16;
    int arow = min(row0 + m16, NN - 1);   // clamp tail reads; stores are guarded

    // ---- stage 1 ----
    f32x4 acc[8];
#pragma unroll
    for (int ct = 0; ct < 8; ct++) acc[ct] = (f32x4){0.f, 0.f, 0.f, 0.f};
#pragma unroll
    for (int kk = 0; kk < 4; kk++) {
        bf16x8 a = *(const bf16x8*)&Abf[(size_t)arow * D + kk * 32 + q * 8];
#pragma unroll
        for (int ct = 0; ct < 8; ct++) {
            bf16x8 b = *(const bf16x8*)&Wl[(ct * 16 + m16) * WS + kk * 32 + q * 8];
            acc[ct] = __builtin_amdgcn_mfma_f32_16x16x32_bf16(a, b, acc[ct], 0, 0, 0);
        }
    }
    // bias + relu -> per-wave T tile (row-major bf16, ready as stage-2 A-frags)
#pragma unroll
    for (int ct = 0; ct < 8; ct++) {
        float bv = b1[ct * 16 + m16];
#pragma unroll
        for (int r = 0; r < 4; r++) {
            float v = fmaxf(acc[ct][r] + bv, 0.f);
            Tl[wid][(q * 4 + r) * WS + ct * 16 + m16] = (__bf16)v;
        }
    }
    __syncthreads();   // all waves done with W1 before overwrite
    {   // stage W2^T over the same buffer
        const uint4* src = (const uint4*)Wt2;
        uint4* dst = (uint4*)Wl;
        for (int i = t; i < D * WS / 8; i += 256) dst[i] = src[i];
    }
    __syncthreads();

    // ---- stage 2 ----
#pragma unroll
    for (int ct = 0; ct < 8; ct++) acc[ct] = (f32x4){0.f, 0.f, 0.f, 0.f};
#pragma unroll
    for (int kk = 0; kk < 4; kk++) {
        bf16x8 a = *(const bf16x8*)&Tl[wid][m16 * WS + kk * 32 + q * 8];
#pragma unroll
        for (int ct = 0; ct < 8; ct++) {
            bf16x8 b = *(const bf16x8*)&Wl[(ct * 16 + m16) * WS + kk * 32 + q * 8];
            acc[ct] = __builtin_amdgcn_mfma_f32_16x16x32_bf16(a, b, acc[ct], 0, 0, 0);
        }
    }
#pragma unroll
    for (int ct = 0; ct < 8; ct++) {
        float bv = b2[ct * 16 + m16];
#pragma unroll
        for (int r = 0; r < 4; r++) {
            int row = row0 + q * 4 + r;
            if (row < NN) C[(size_t)row * D + ct * 16 + m16] = acc[ct][r] + bv;
        }
    }
}

// ---------------- CSR aggregate: one WAVE per dst node, x8 unrolled gathers ----------------
// Also emits the bf16 copy of h for the next layer's MFMA A-frags.

__global__ __launch_bounds__(256) void aggregate_kernel(
    const float2* __restrict__ Mmsg2, const float2* __restrict__ Mself2,
    const int* __restrict__ row_ptr, const float2* __restrict__ meta,
    float2* __restrict__ out2, bf16x2* __restrict__ hbf2) {
    int wid = (blockIdx.x * 256 + threadIdx.x) >> 6;   // node id (2500*4 = NN)
    int lane = threadIdx.x & 63;
    int beg = row_ptr[wid], end = row_ptr[wid + 1];
    float a0[8], a1[8];
#pragma unroll
    for (int u = 0; u < 8; u++) { a0[u] = 0.f; a1[u] = 0.f; }
    for (int j = beg; j < end; j += 8) {
        float2 m[8];
#pragma unroll
        for (int u = 0; u < 8; u++) {
            int jj = j + u;
            m[u] = (jj < end) ? meta[jj] : make_float2(__int_as_float(0), 0.f);
        }
        float2 g[8];
#pragma unroll
        for (int u = 0; u < 8; u++)
            g[u] = Mmsg2[(size_t)__float_as_int(m[u].x) * 64 + lane];
#pragma unroll
        for (int u = 0; u < 8; u++) {
            a0[u] = fmaf(m[u].y, g[u].x, a0[u]);
            a1[u] = fmaf(m[u].y, g[u].y, a1[u]);
        }
    }
    float s0 = ((a0[0] + a0[1]) + (a0[2] + a0[3])) + ((a0[4] + a0[5]) + (a0[6] + a0[7]));
    float s1 = ((a1[0] + a1[1]) + (a1[2] + a1[3])) + ((a1[4] + a1[5]) + (a1[6] + a1[7]));
    float2 sv = Mself2[(size_t)wid * 64 + lane];
    float2 res = make_float2(fmaxf(s0 + sv.x, 0.f), fmaxf(s1 + sv.y, 0.f));
    out2[(size_t)wid * 64 + lane] = res;               // canonical f32 (graded)
    bf16x2 hb;
    hb.x = (__bf16)res.x;
    hb.y = (__bf16)res.y;
    hbf2[(size_t)wid * 64 + lane] = hb;                // bf16 h for next layer
}

// ---------------- fused scoring + softmax + weighted sum ----------------

__global__ __launch_bounds__(64) void score_finalize_kernel(
    const float* __restrict__ st, const float* __restrict__ W1,
    const float* __restrict__ b1, const float* __restrict__ w2,
    const float* __restrict__ b2, float* __restrict__ out, float* __restrict__ lw_out) {
    __shared__ float Sl[3][8][D];   // 12 KiB, wave-private
    int lane = threadIdx.x;
    int row0 = blockIdx.x * 8;      // 1250*8 = NN exactly
    for (int l = 0; l < 3; l++) {
        const float4* src = (const float4*)(st + (size_t)l * NF + (size_t)row0 * D);
        float4* dst = (float4*)&Sl[l][0][0];
#pragma unroll
        for (int i = 0; i < 4; i++) dst[lane + 64 * i] = src[lane + 64 * i];
    }
    __syncthreads();

    float2 w2v = *(const float2*)&w2[2 * lane];
    float2 b1v = *(const float2*)&b1[2 * lane];
    float bb = b2[0];
    float sc[3][8];

    for (int l = 0; l < 3; l++) {
        float acc[8][2];
#pragma unroll
        for (int r = 0; r < 8; r++) { acc[r][0] = 0.f; acc[r][1] = 0.f; }
#pragma unroll 2
        for (int k = 0; k < D; k += 4) {
            float2 w[4];
#pragma unroll
            for (int kk = 0; kk < 4; kk++) w[kk] = *(const float2*)&W1[(k + kk) * D + 2 * lane];
#pragma unroll
            for (int r = 0; r < 8; r++) {
                float4 a = *(const float4*)&Sl[l][r][k];
                acc[r][0] = fmaf(a.x, w[0].x, fmaf(a.y, w[1].x, fmaf(a.z, w[2].x, fmaf(a.w, w[3].x, acc[r][0]))));
                acc[r][1] = fmaf(a.x, w[0].y, fmaf(a.y, w[1].y, fmaf(a.z, w[2].y, fmaf(a.w, w[3].y, acc[r][1]))));
            }
        }
#pragma unroll
        for (int r = 0; r < 8; r++) {
            float p = fmaxf(acc[r][0] + b1v.x, 0.f) * w2v.x +
                      fmaxf(acc[r][1] + b1v.y, 0.f) * w2v.y;
#pragma unroll
            for (int off = 1; off < 64; off <<= 1) p += __shfl_xor(p, off);
            sc[l][r] = p + bb;
        }
    }

#pragma unroll
    for (int r = 0; r < 8; r++) {
        float s0 = sc[0][r], s1 = sc[1][r], s2 = sc[2][r];
        float m = fmaxf(s0, fmaxf(s1, s2));
        float e0 = expf(s0 - m), e1 = expf(s1 - m), e2 = expf(s2 - m);
        float inv = 1.f / (e0 + e1 + e2);
        float wl0 = e0 * inv, wl1 = e1 * inv, wl2 = e2 * inv;
        float2 v0 = *(const float2*)&Sl[0][r][2 * lane];
        float2 v1 = *(const float2*)&Sl[1][r][2 * lane];
        float2 v2 = *(const float2*)&Sl[2][r][2 * lane];
        *(float2*)&out[(size_t)(row0 + r) * D + 2 * lane] =
            make_float2(wl0 * v0.x + wl1 * v1.x + wl2 * v2.x,
                        wl0 * v0.y + wl1 * v1.y + wl2 * v2.y);
        if (lane == 0) {
            lw_out[row0 + r] = wl0;
            lw_out[NN + row0 + r] = wl1;
            lw_out[2 * NN + row0 + r] = wl2;
        }
    }
}

extern "C" void kernel_launch(void* const* d_in, const int* in_sizes, int n_in,
                              void* d_out, int out_size, void* d_ws, size_t ws_size,
                              hipStream_t stream) {
    const float* x = (const float*)d_in[0];
    const int* ei = (const int*)d_in[1];
    const float* conf = (const float*)d_in[2];
    const float* msg_W1 = (const float*)d_in[3];
    const float* msg_b1 = (const float*)d_in[4];
    const float* msg_W2 = (const float*)d_in[5];
    const float* msg_b2 = (const float*)d_in[6];
    const float* self_W1 = (const float*)d_in[7];
    const float* self_b1 = (const float*)d_in[8];
    const float* self_W2 = (const float*)d_in[9];
    const float* self_b2 = (const float*)d_in[10];
    const float* score_W1 = (const float*)d_in[11];
    const float* score_b1 = (const float*)d_in[12];
    const float* score_W2 = (const float*)d_in[13];
    const float* score_b2 = (const float*)d_in[14];

    float* out = (float*)d_out;                 // [NN,D]
    float* out_stacked = out + NF;              // [3,NN,D]  (canonical, graded)
    float* out_lw = out + 4 * (size_t)NF;       // [3,NN]

    float* w = (float*)d_ws;
    float* Mmsg = w;                               // NF f32 canonical
    float* Mself = w + (size_t)NF;                 // NF
    float2* meta = (float2*)(w + 2 * (size_t)NF);  // NE x {src, weight}
    __bf16* xbf = (__bf16*)(meta + NE);            // NF bf16
    __bf16* hbf = xbf + (size_t)NF;                // NF bf16
    __bf16* wt = hbf + (size_t)NF;                 // 13 * D * WS bf16
    int* row_ptr = (int*)(wt + 13 * (size_t)D * WS);  // NN+1
    int* cnt = row_ptr + NN + 1;                   // NN
    int* cursor = cnt + NN;                        // NN

    const size_t MAT = (size_t)D * WS;
    const int GE = (NE + 255) / 256;  // 2500
    const int GN = (NN + 255) / 256;  // 40

    zero_cnt_kernel<<<GN, 256, 0, stream>>>(cnt);
    hist_kernel<<<GE, 256, 0, stream>>>(ei, cnt);
    scan_kernel<<<1, 256, 0, stream>>>(cnt, row_ptr, cursor);
    scatter_kernel<<<GE, 256, 0, stream>>>(ei, conf, cursor, meta);
    cvt_x_kernel<<<NF / 512, 256, 0, stream>>>((const float2*)x, (bf16x2*)xbf);
    prep_wt_kernel<<<13, 256, 0, stream>>>(msg_W1, msg_W2, self_W1, self_W2, score_W1, wt);

    for (int l = 0; l < 3; l++) {
        const __bf16* a_in = (l == 0) ? xbf : hbf;
        mlp_pair_mfma<<<dim3((NN + 63) / 64, 2), 256, 0, stream>>>(
            a_in,
            wt + (size_t)l * MAT, msg_b1 + (size_t)l * D,            // msg W1^T
            wt + (size_t)(3 + l) * MAT, msg_b2 + (size_t)l * D, Mmsg,  // msg W2^T
            wt + (size_t)(6 + l) * MAT, self_b1 + (size_t)l * D,     // self W1^T
            wt + (size_t)(9 + l) * MAT, self_b2 + (size_t)l * D, Mself);
        aggregate_kernel<<<NN / 4, 256, 0, stream>>>(
            (const float2*)Mmsg, (const float2*)Mself, row_ptr, meta,
            (float2*)(out_stacked + (size_t)l * NF),
            (bf16x2*)hbf);
    }

    score_finalize_kernel<<<NN / 8, 64, 0, stream>>>(out_stacked, score_W1, score_b1,
                                                     score_W2, score_b2, out, out_lw);
}

// Round 7
// 402.569 us; speedup vs baseline: 1.4520x; 1.1745x over previous
//
#include <hip/hip_runtime.h>

#define NN 10000
#define NE 640000
#define D 128
#define NF (NN * D)
#define WS 136   // padded bf16 row stride: 272 B = 16B-aligned, 2-way-free LDS banks

typedef __bf16 bf16x8 __attribute__((ext_vector_type(8)));
typedef __bf16 bf16x2 __attribute__((ext_vector_type(2)));
typedef float f32x4 __attribute__((ext_vector_type(4)));

// ---------------- CSR build ----------------

__global__ void zero_cnt_kernel(int* __restrict__ cnt) {
    int i = blockIdx.x * 256 + threadIdx.x;
    if (i < NN) cnt[i] = 0;
}

__global__ void hist_kernel(const int* __restrict__ ei, int* __restrict__ cnt) {
    int e = blockIdx.x * 256 + threadIdx.x;
    if (e < NE) atomicAdd(&cnt[ei[NE + e]], 1);
}

__global__ void scan_kernel(const int* __restrict__ cnt, int* __restrict__ row_ptr,
                            int* __restrict__ cursor) {
    __shared__ int lds[256];
    int t = threadIdx.x;
    const int CH = (NN + 255) / 256;  // 40
    int base = t * CH;
    int s = 0;
    for (int i = 0; i < CH; i++) {
        int idx = base + i;
        if (idx < NN) s += cnt[idx];
    }
    lds[t] = s;
    __syncthreads();
    for (int off = 1; off < 256; off <<= 1) {
        int v = (t >= off) ? lds[t - off] : 0;
        __syncthreads();
        lds[t] += v;
        __syncthreads();
    }
    int run = (t == 0) ? 0 : lds[t - 1];
    for (int i = 0; i < CH; i++) {
        int idx = base + i;
        if (idx < NN) {
            row_ptr[idx] = run;
            cursor[idx] = run;
            run += cnt[idx];
        }
    }
    if (t == 255) row_ptr[NN] = lds[255];
}

__global__ void scatter_kernel(const int* __restrict__ ei, const float* __restrict__ conf,
                               int* __restrict__ cursor, float2* __restrict__ meta) {
    int e = blockIdx.x * 256 + threadIdx.x;
    if (e >= NE) return;
    int s = ei[e];
    int d = ei[NE + e];
    int pos = atomicAdd(&cursor[d], 1);
    meta[pos] = make_float2(__int_as_float(s), expf(-fabsf(conf[s] - conf[d])));
}

// ---------------- prep: x -> bf16, W -> bf16 transposed (Wt[n][k], stride WS) ----------------

__global__ void cvt_x_kernel(const float2* __restrict__ x2, bf16x2* __restrict__ xbf) {
    int i = blockIdx.x * 256 + threadIdx.x;  // NF/2 = 640000
    float2 v = x2[i];
    bf16x2 o;
    o.x = (__bf16)v.x;
    o.y = (__bf16)v.y;
    xbf[i] = o;
}

// mats: 0-2 msg_W1[l], 3-5 msg_W2[l], 6-8 self_W1[l], 9-11 self_W2[l], 12 score_W1
__global__ __launch_bounds__(256) void prep_wt_kernel(
    const float* __restrict__ mW1, const float* __restrict__ mW2,
    const float* __restrict__ sW1, const float* __restrict__ sW2,
    const float* __restrict__ scW1, __bf16* __restrict__ wt) {
    int m = blockIdx.x;
    const float* W = (m < 3)   ? mW1 + (size_t)m * D * D
                   : (m < 6)   ? mW2 + (size_t)(m - 3) * D * D
                   : (m < 9)   ? sW1 + (size_t)(m - 6) * D * D
                   : (m < 12)  ? sW2 + (size_t)(m - 9) * D * D
                               : scW1;
    __bf16* o = wt + (size_t)m * D * WS;
    for (int i = threadIdx.x; i < D * D; i += 256) {
        int k = i >> 7, n = i & 127;
        o[n * WS + k] = (__bf16)W[i];
    }
}

// ---------------- fused 2-layer MLP via bf16 MFMA ----------------
// Block = 4 waves x 16 rows. W^T staged in LDS (W1 then W2 through one buffer).
// blockIdx.y==0: msg problem, output written as bf16 (Mbf) so the aggregate's
// gather set is 2.56 MB and stays L2-resident. blockIdx.y==1: self, f32 out.

__global__ __launch_bounds__(256) void mlp_pair_mfma(
    const __bf16* __restrict__ Abf,
    const __bf16* __restrict__ Wt1a, const float* __restrict__ b1a,
    const __bf16* __restrict__ Wt2a, const float* __restrict__ b2a, __bf16* __restrict__ Mbf,
    const __bf16* __restrict__ Wt1b, const float* __restrict__ b1b,
    const __bf16* __restrict__ Wt2b, const float* __restrict__ b2b, float* __restrict__ Cself) {
    const __bf16* Wt1 = blockIdx.y ? Wt1b : Wt1a;
    const float* b1 = blockIdx.y ? b1b : b1a;
    const __bf16* Wt2 = blockIdx.y ? Wt2b : Wt2a;
    const float* b2 = blockIdx.y ? b2b : b2a;

    __shared__ __align__(16) __bf16 Wl[D * WS];       // 34816 B: W1^T, then W2^T
    __shared__ __align__(16) __bf16 Tl[4][16 * WS];   // 4352 B per wave
    int t = threadIdx.x;
    int wid = t >> 6, lane = t & 63;
    int m16 = lane & 15, q = lane >> 4;

    {   // stage W1^T
        const uint4* src = (const uint4*)Wt1;
        uint4* dst = (uint4*)Wl;
        for (int i = t; i < D * WS / 8; i += 256) dst[i] = src[i];
    }
    __syncthreads();

    int row0 = blockIdx.x * 64 + wid * 16;
    int arow = min(row0 + m16, NN - 1);   // clamp tail reads; stores are guarded

    // ---- stage 1 ----
    f32x4 acc[8];
#pragma unroll
    for (int ct = 0; ct < 8; ct++) acc[ct] = (f32x4){0.f, 0.f, 0.f, 0.f};
#pragma unroll
    for (int kk = 0; kk < 4; kk++) {
        bf16x8 a = *(const bf16x8*)&Abf[(size_t)arow * D + kk * 32 + q * 8];
#pragma unroll
        for (int ct = 0; ct < 8; ct++) {
            bf16x8 b = *(const bf16x8*)&Wl[(ct * 16 + m16) * WS + kk * 32 + q * 8];
            acc[ct] = __builtin_amdgcn_mfma_f32_16x16x32_bf16(a, b, acc[ct], 0, 0, 0);
        }
    }
#pragma unroll
    for (int ct = 0; ct < 8; ct++) {
        float bv = b1[ct * 16 + m16];
#pragma unroll
        for (int r = 0; r < 4; r++) {
            float v = fmaxf(acc[ct][r] + bv, 0.f);
            Tl[wid][(q * 4 + r) * WS + ct * 16 + m16] = (__bf16)v;
        }
    }
    __syncthreads();   // all waves done with W1 before overwrite
    {   // stage W2^T
        const uint4* src = (const uint4*)Wt2;
        uint4* dst = (uint4*)Wl;
        for (int i = t; i < D * WS / 8; i += 256) dst[i] = src[i];
    }
    __syncthreads();

    // ---- stage 2 ----
#pragma unroll
    for (int ct = 0; ct < 8; ct++) acc[ct] = (f32x4){0.f, 0.f, 0.f, 0.f};
#pragma unroll
    for (int kk = 0; kk < 4; kk++) {
        bf16x8 a = *(const bf16x8*)&Tl[wid][m16 * WS + kk * 32 + q * 8];
#pragma unroll
        for (int ct = 0; ct < 8; ct++) {
            bf16x8 b = *(const bf16x8*)&Wl[(ct * 16 + m16) * WS + kk * 32 + q * 8];
            acc[ct] = __builtin_amdgcn_mfma_f32_16x16x32_bf16(a, b, acc[ct], 0, 0, 0);
        }
    }
    if (blockIdx.y == 0) {   // msg -> bf16 (L2-resident gather set)
#pragma unroll
        for (int ct = 0; ct < 8; ct++) {
            float bv = b2[ct * 16 + m16];
#pragma unroll
            for (int r = 0; r < 4; r++) {
                int row = row0 + q * 4 + r;
                if (row < NN) Mbf[(size_t)row * D + ct * 16 + m16] = (__bf16)(acc[ct][r] + bv);
            }
        }
    } else {                 // self -> f32 (streamed once, keep precision)
#pragma unroll
        for (int ct = 0; ct < 8; ct++) {
            float bv = b2[ct * 16 + m16];
#pragma unroll
            for (int r = 0; r < 4; r++) {
                int row = row0 + q * 4 + r;
                if (row < NN) Cself[(size_t)row * D + ct * 16 + m16] = acc[ct][r] + bv;
            }
        }
    }
}

// ---------------- CSR aggregate: one WAVE per dst node, x8 unrolled bf16 gathers ----------------
// Gather set = bf16 Mbf (2.56 MB, fits 4 MiB/XCD L2). One dword/lane per edge.
// Emits f32 stacked slice (graded, + finalize input) and bf16 slice (next-layer
// MFMA input + scoring input).

__global__ __launch_bounds__(256) void aggregate_kernel(
    const unsigned int* __restrict__ Mbf32, const float2* __restrict__ Mself2,
    const int* __restrict__ row_ptr, const float2* __restrict__ meta,
    float2* __restrict__ out2, bf16x2* __restrict__ stbf2) {
    int wid = (blockIdx.x * 256 + threadIdx.x) >> 6;   // node id (2500*4 = NN)
    int lane = threadIdx.x & 63;
    int beg = row_ptr[wid], end = row_ptr[wid + 1];
    float a0[8], a1[8];
#pragma unroll
    for (int u = 0; u < 8; u++) { a0[u] = 0.f; a1[u] = 0.f; }
    for (int j = beg; j < end; j += 8) {
        float2 m[8];
#pragma unroll
        for (int u = 0; u < 8; u++) {
            int jj = j + u;
            m[u] = (jj < end) ? meta[jj] : make_float2(__int_as_float(0), 0.f);
        }
        unsigned int g[8];
#pragma unroll
        for (int u = 0; u < 8; u++)
            g[u] = Mbf32[(size_t)__float_as_int(m[u].x) * 64 + lane];  // 256 B/wave
#pragma unroll
        for (int u = 0; u < 8; u++) {
            float glo = __uint_as_float(g[u] << 16);          // col 2*lane
            float ghi = __uint_as_float(g[u] & 0xFFFF0000u);  // col 2*lane+1
            a0[u] = fmaf(m[u].y, glo, a0[u]);
            a1[u] = fmaf(m[u].y, ghi, a1[u]);
        }
    }
    float s0 = ((a0[0] + a0[1]) + (a0[2] + a0[3])) + ((a0[4] + a0[5]) + (a0[6] + a0[7]));
    float s1 = ((a1[0] + a1[1]) + (a1[2] + a1[3])) + ((a1[4] + a1[5]) + (a1[6] + a1[7]));
    float2 sv = Mself2[(size_t)wid * 64 + lane];
    float2 res = make_float2(fmaxf(s0 + sv.x, 0.f), fmaxf(s1 + sv.y, 0.f));
    out2[(size_t)wid * 64 + lane] = res;               // canonical f32 (graded)
    bf16x2 hb;
    hb.x = (__bf16)res.x;
    hb.y = (__bf16)res.y;
    stbf2[(size_t)wid * 64 + lane] = hb;               // bf16 copy for MFMA consumers
}

// ---------------- fused scoring (MFMA) + softmax + weighted sum ----------------
// One block per 64 rows. score_W1^T staged once in LDS; per layer: MFMA stage-1,
// relu+dot(w2) in-register, 16-lane butterfly reduce. Then per-row softmax over
// the 3 layers and the weighted sum over the f32 stacked (streamed, coalesced).

__global__ __launch_bounds__(256) void score_finalize_mfma(
    const __bf16* __restrict__ stbf, const float* __restrict__ st,
    const __bf16* __restrict__ Wt1, const float* __restrict__ b1,
    const float* __restrict__ w2, const float* __restrict__ b2,
    float* __restrict__ out, float* __restrict__ lw_out) {
    __shared__ __align__(16) __bf16 Wl[D * WS];   // 34816 B
    __shared__ float sc_l[3][64];
    __shared__ float lw_l[3][64];
    int t = threadIdx.x;
    int wid = t >> 6, lane = t & 63;
    int m16 = lane & 15, q = lane >> 4;
    int row0 = blockIdx.x * 64;

    {
        const uint4* src = (const uint4*)Wt1;
        uint4* dst = (uint4*)Wl;
        for (int i = t; i < D * WS / 8; i += 256) dst[i] = src[i];
    }
    __syncthreads();

    int arow = min(row0 + wid * 16 + m16, NN - 1);
    float bb = b2[0];

    for (int l = 0; l < 3; l++) {
        const __bf16* A = stbf + (size_t)l * NF;
        f32x4 acc[8];
#pragma unroll
        for (int ct = 0; ct < 8; ct++) acc[ct] = (f32x4){0.f, 0.f, 0.f, 0.f};
#pragma unroll
        for (int kk = 0; kk < 4; kk++) {
            bf16x8 a = *(const bf16x8*)&A[(size_t)arow * D + kk * 32 + q * 8];
#pragma unroll
            for (int ct = 0; ct < 8; ct++) {
                bf16x8 b = *(const bf16x8*)&Wl[(ct * 16 + m16) * WS + kk * 32 + q * 8];
                acc[ct] = __builtin_amdgcn_mfma_f32_16x16x32_bf16(a, b, acc[ct], 0, 0, 0);
            }
        }
        float p[4] = {0.f, 0.f, 0.f, 0.f};
#pragma unroll
        for (int ct = 0; ct < 8; ct++) {
            float bv = b1[ct * 16 + m16];
            float wv = w2[ct * 16 + m16];
#pragma unroll
            for (int r = 0; r < 4; r++) p[r] += fmaxf(acc[ct][r] + bv, 0.f) * wv;
        }
#pragma unroll
        for (int r = 0; r < 4; r++) {
#pragma unroll
            for (int off = 1; off < 16; off <<= 1) p[r] += __shfl_xor(p[r], off);
            if (m16 == 0) sc_l[l][wid * 16 + q * 4 + r] = p[r] + bb;
        }
    }
    __syncthreads();

    if (t < 64) {   // per-row softmax over layers
        int row = row0 + t;
        float s0 = sc_l[0][t], s1 = sc_l[1][t], s2 = sc_l[2][t];
        float m = fmaxf(s0, fmaxf(s1, s2));
        float e0 = expf(s0 - m), e1 = expf(s1 - m), e2 = expf(s2 - m);
        float inv = 1.f / (e0 + e1 + e2);
        lw_l[0][t] = e0 * inv;
        lw_l[1][t] = e1 * inv;
        lw_l[2][t] = e2 * inv;
        if (row < NN) {
            lw_out[row] = e0 * inv;
            lw_out[NN + row] = e1 * inv;
            lw_out[2 * NN + row] = e2 * inv;
        }
    }
    __syncthreads();

    // weighted sum over f32 stacked (64 rows x 32 float4)
    for (int i = t; i < 64 * 32; i += 256) {
        int r = i >> 5, c4 = i & 31;
        int row = row0 + r;
        if (row >= NN) break;
        float4 v0 = ((const float4*)(st + (size_t)row * D))[c4];
        float4 v1 = ((const float4*)(st + (size_t)NF + (size_t)row * D))[c4];
        float4 v2 = ((const float4*)(st + 2 * (size_t)NF + (size_t)row * D))[c4];
        float w0 = lw_l[0][r], w1 = lw_l[1][r], w2v = lw_l[2][r];
        float4 o;
        o.x = w0 * v0.x + w1 * v1.x + w2v * v2.x;
        o.y = w0 * v0.y + w1 * v1.y + w2v * v2.y;
        o.z = w0 * v0.z + w1 * v1.z + w2v * v2.z;
        o.w = w0 * v0.w + w1 * v1.w + w2v * v2.w;
        ((float4*)(out + (size_t)row * D))[c4] = o;
    }
}

extern "C" void kernel_launch(void* const* d_in, const int* in_sizes, int n_in,
                              void* d_out, int out_size, void* d_ws, size_t ws_size,
                              hipStream_t stream) {
    const float* x = (const float*)d_in[0];
    const int* ei = (const int*)d_in[1];
    const float* conf = (const float*)d_in[2];
    const float* msg_W1 = (const float*)d_in[3];
    const float* msg_b1 = (const float*)d_in[4];
    const float* msg_W2 = (const float*)d_in[5];
    const float* msg_b2 = (const float*)d_in[6];
    const float* self_W1 = (const float*)d_in[7];
    const float* self_b1 = (const float*)d_in[8];
    const float* self_W2 = (const float*)d_in[9];
    const float* self_b2 = (const float*)d_in[10];
    const float* score_W1 = (const float*)d_in[11];
    const float* score_b1 = (const float*)d_in[12];
    const float* score_W2 = (const float*)d_in[13];
    const float* score_b2 = (const float*)d_in[14];

    float* out = (float*)d_out;                 // [NN,D]
    float* out_stacked = out + NF;              // [3,NN,D]  (canonical f32, graded)
    float* out_lw = out + 4 * (size_t)NF;       // [3,NN]

    float* w = (float*)d_ws;
    float* Mself = w;                              // NF f32
    float2* meta = (float2*)(w + (size_t)NF);      // NE x {src, weight}
    __bf16* xbf = (__bf16*)(meta + NE);            // NF bf16
    __bf16* stbf = xbf + (size_t)NF;               // 3*NF bf16 (per-layer stacked)
    __bf16* Mbf = stbf + 3 * (size_t)NF;           // NF bf16 (msg MLP out, gather set)
    __bf16* wt = Mbf + (size_t)NF;                 // 13 * D * WS bf16
    int* row_ptr = (int*)(wt + 13 * (size_t)D * WS);  // NN+1
    int* cnt = row_ptr + NN + 1;                   // NN
    int* cursor = cnt + NN;                        // NN

    const size_t MAT = (size_t)D * WS;
    const int GE = (NE + 255) / 256;  // 2500
    const int GN = (NN + 255) / 256;  // 40
    const int GB64 = (NN + 63) / 64;  // 157

    zero_cnt_kernel<<<GN, 256, 0, stream>>>(cnt);
    hist_kernel<<<GE, 256, 0, stream>>>(ei, cnt);
    scan_kernel<<<1, 256, 0, stream>>>(cnt, row_ptr, cursor);
    scatter_kernel<<<GE, 256, 0, stream>>>(ei, conf, cursor, meta);
    cvt_x_kernel<<<NF / 512, 256, 0, stream>>>((const float2*)x, (bf16x2*)xbf);
    prep_wt_kernel<<<13, 256, 0, stream>>>(msg_W1, msg_W2, self_W1, self_W2, score_W1, wt);

    for (int l = 0; l < 3; l++) {
        const __bf16* a_in = (l == 0) ? xbf : stbf + (size_t)(l - 1) * NF;
        mlp_pair_mfma<<<dim3(GB64, 2), 256, 0, stream>>>(
            a_in,
            wt + (size_t)l * MAT, msg_b1 + (size_t)l * D,
            wt + (size_t)(3 + l) * MAT, msg_b2 + (size_t)l * D, Mbf,
            wt + (size_t)(6 + l) * MAT, self_b1 + (size_t)l * D,
            wt + (size_t)(9 + l) * MAT, self_b2 + (size_t)l * D, Mself);
        aggregate_kernel<<<NN / 4, 256, 0, stream>>>(
            (const unsigned int*)Mbf, (const float2*)Mself, row_ptr, meta,
            (float2*)(out_stacked + (size_t)l * NF),
            (bf16x2*)(stbf + (size_t)l * NF));
    }

    score_finalize_mfma<<<GB64, 256, 0, stream>>>(
        stbf, out_stacked, wt + 12 * MAT, score_b1, score_W2, score_b2, out, out_lw);
}

// Round 8
// 385.655 us; speedup vs baseline: 1.5157x; 1.0439x over previous
//
#include <hip/hip_runtime.h>

#define NN 10000
#define NE 640000
#define D 128
#define NF (NN * D)
#define WS 136   // padded bf16 row stride: 272 B = 16B-aligned, 2-way-free LDS banks
#define WBYTES (D * WS * 2)   // 34816 B per W^T matrix
#define WCHUNKS (WBYTES / 1024)  // 34 async 1KB wave-chunks

typedef __bf16 bf16x8 __attribute__((ext_vector_type(8)));
typedef __bf16 bf16x4 __attribute__((ext_vector_type(4)));
typedef __bf16 bf16x2 __attribute__((ext_vector_type(2)));
typedef float f32x4 __attribute__((ext_vector_type(4)));

// async global->LDS, 16B per lane, 1 KB per wave-call [m97-verified width=16]
__device__ __forceinline__ void async_copy16(const void* g, void* l) {
    __builtin_amdgcn_global_load_lds(
        (const __attribute__((address_space(1))) unsigned int*)g,
        (__attribute__((address_space(3))) unsigned int*)l, 16, 0, 0);
}

// ---------------- CSR build ----------------

__global__ void zero_cnt_kernel(int* __restrict__ cnt) {
    int i = blockIdx.x * 256 + threadIdx.x;
    if (i < NN) cnt[i] = 0;
}

__global__ void hist_kernel(const int* __restrict__ ei, int* __restrict__ cnt) {
    int e = blockIdx.x * 256 + threadIdx.x;
    if (e < NE) atomicAdd(&cnt[ei[NE + e]], 1);
}

__global__ void scan_kernel(const int* __restrict__ cnt, int* __restrict__ row_ptr,
                            int* __restrict__ cursor) {
    __shared__ int lds[256];
    int t = threadIdx.x;
    const int CH = (NN + 255) / 256;  // 40
    int base = t * CH;
    int s = 0;
    for (int i = 0; i < CH; i++) {
        int idx = base + i;
        if (idx < NN) s += cnt[idx];
    }
    lds[t] = s;
    __syncthreads();
    for (int off = 1; off < 256; off <<= 1) {
        int v = (t >= off) ? lds[t - off] : 0;
        __syncthreads();
        lds[t] += v;
        __syncthreads();
    }
    int run = (t == 0) ? 0 : lds[t - 1];
    for (int i = 0; i < CH; i++) {
        int idx = base + i;
        if (idx < NN) {
            row_ptr[idx] = run;
            cursor[idx] = run;
            run += cnt[idx];
        }
    }
    if (t == 255) row_ptr[NN] = lds[255];
}

__global__ void scatter_kernel(const int* __restrict__ ei, const float* __restrict__ conf,
                               int* __restrict__ cursor, float2* __restrict__ meta) {
    int e = blockIdx.x * 256 + threadIdx.x;
    if (e >= NE) return;
    int s = ei[e];
    int d = ei[NE + e];
    int pos = atomicAdd(&cursor[d], 1);
    meta[pos] = make_float2(__int_as_float(s), expf(-fabsf(conf[s] - conf[d])));
}

// ---------------- prep: x -> bf16, W -> bf16 transposed (Wt[n][k], stride WS) ----------------

__global__ void cvt_x_kernel(const float2* __restrict__ x2, bf16x2* __restrict__ xbf) {
    int i = blockIdx.x * 256 + threadIdx.x;  // NF/2 = 640000
    float2 v = x2[i];
    bf16x2 o;
    o.x = (__bf16)v.x;
    o.y = (__bf16)v.y;
    xbf[i] = o;
}

// mats: 0-2 msg_W1[l], 3-5 msg_W2[l], 6-8 self_W1[l], 9-11 self_W2[l], 12 score_W1
__global__ __launch_bounds__(256) void prep_wt_kernel(
    const float* __restrict__ mW1, const float* __restrict__ mW2,
    const float* __restrict__ sW1, const float* __restrict__ sW2,
    const float* __restrict__ scW1, __bf16* __restrict__ wt) {
    int m = blockIdx.x;
    const float* W = (m < 3)   ? mW1 + (size_t)m * D * D
                   : (m < 6)   ? mW2 + (size_t)(m - 3) * D * D
                   : (m < 9)   ? sW1 + (size_t)(m - 6) * D * D
                   : (m < 12)  ? sW2 + (size_t)(m - 9) * D * D
                               : scW1;
    __bf16* o = wt + (size_t)m * D * WS;
    for (int i = threadIdx.x; i < D * D; i += 256) {
        int k = i >> 7, n = i & 127;
        o[n * WS + k] = (__bf16)W[i];
    }
}

// ---------------- fused 2-layer MLP via bf16 MFMA ----------------
// Block = 2 waves x 16 rows (626 blocks -> ~2.4/CU for staging overlap).
// W1^T and W2^T async-staged up-front into double-buffered LDS; ONE barrier,
// then straight-line compute (T tile is wave-private -> no second barrier).
// blockIdx.y==0: msg problem -> bf16 out (L2-resident gather set); ==1: self -> f32.

__global__ __launch_bounds__(128) void mlp_pair_mfma(
    const __bf16* __restrict__ Abf,
    const __bf16* __restrict__ Wt1a, const float* __restrict__ b1a,
    const __bf16* __restrict__ Wt2a, const float* __restrict__ b2a, __bf16* __restrict__ Mbf,
    const __bf16* __restrict__ Wt1b, const float* __restrict__ b1b,
    const __bf16* __restrict__ Wt2b, const float* __restrict__ b2b, float* __restrict__ Cself) {
    const __bf16* Wt1 = blockIdx.y ? Wt1b : Wt1a;
    const float* b1 = blockIdx.y ? b1b : b1a;
    const __bf16* Wt2 = blockIdx.y ? Wt2b : Wt2a;
    const float* b2 = blockIdx.y ? b2b : b2a;

    __shared__ __align__(16) __bf16 Wl[2][D * WS];    // 2 x 34816 B
    __shared__ __align__(16) __bf16 Tl[2][16 * WS];   // 4352 B per wave
    int t = threadIdx.x;
    int wid = t >> 6, lane = t & 63;
    int m16 = lane & 15, q = lane >> 4;

    // async stage both W^T buffers; lane-ordered contiguous 1KB chunks
    for (int c = wid; c < WCHUNKS; c += 2) {
        async_copy16((const char*)Wt1 + c * 1024 + lane * 16,
                     (char*)&Wl[0][0] + c * 1024 + lane * 16);
        async_copy16((const char*)Wt2 + c * 1024 + lane * 16,
                     (char*)&Wl[1][0] + c * 1024 + lane * 16);
    }
    __syncthreads();   // drains vmcnt (all staging) once

    int row0 = blockIdx.x * 32 + wid * 16;
    int arow = min(row0 + m16, NN - 1);   // clamp tail reads; stores are guarded

    // ---- stage 1 ----
    f32x4 acc[8];
#pragma unroll
    for (int ct = 0; ct < 8; ct++) acc[ct] = (f32x4){0.f, 0.f, 0.f, 0.f};
#pragma unroll
    for (int kk = 0; kk < 4; kk++) {
        bf16x8 a = *(const bf16x8*)&Abf[(size_t)arow * D + kk * 32 + q * 8];
#pragma unroll
        for (int ct = 0; ct < 8; ct++) {
            bf16x8 b = *(const bf16x8*)&Wl[0][(ct * 16 + m16) * WS + kk * 32 + q * 8];
            acc[ct] = __builtin_amdgcn_mfma_f32_16x16x32_bf16(a, b, acc[ct], 0, 0, 0);
        }
    }
#pragma unroll
    for (int ct = 0; ct < 8; ct++) {
        float bv = b1[ct * 16 + m16];
#pragma unroll
        for (int r = 0; r < 4; r++) {
            float v = fmaxf(acc[ct][r] + bv, 0.f);
            Tl[wid][(q * 4 + r) * WS + ct * 16 + m16] = (__bf16)v;
        }
    }
    // no barrier: Tl[wid] is wave-private, DS ops are in-order within a wave

    // ---- stage 2 ----
#pragma unroll
    for (int ct = 0; ct < 8; ct++) acc[ct] = (f32x4){0.f, 0.f, 0.f, 0.f};
#pragma unroll
    for (int kk = 0; kk < 4; kk++) {
        bf16x8 a = *(const bf16x8*)&Tl[wid][m16 * WS + kk * 32 + q * 8];
#pragma unroll
        for (int ct = 0; ct < 8; ct++) {
            bf16x8 b = *(const bf16x8*)&Wl[1][(ct * 16 + m16) * WS + kk * 32 + q * 8];
            acc[ct] = __builtin_amdgcn_mfma_f32_16x16x32_bf16(a, b, acc[ct], 0, 0, 0);
        }
    }
    if (blockIdx.y == 0) {   // msg -> bf16 (L2-resident gather set)
#pragma unroll
        for (int ct = 0; ct < 8; ct++) {
            float bv = b2[ct * 16 + m16];
#pragma unroll
            for (int r = 0; r < 4; r++) {
                int row = row0 + q * 4 + r;
                if (row < NN) Mbf[(size_t)row * D + ct * 16 + m16] = (__bf16)(acc[ct][r] + bv);
            }
        }
    } else {                 // self -> f32 (streamed once, keep precision)
#pragma unroll
        for (int ct = 0; ct < 8; ct++) {
            float bv = b2[ct * 16 + m16];
#pragma unroll
            for (int r = 0; r < 4; r++) {
                int row = row0 + q * 4 + r;
                if (row < NN) Cself[(size_t)row * D + ct * 16 + m16] = acc[ct][r] + bv;
            }
        }
    }
}

// ---------------- CSR aggregate: one WAVE per node, 2 edges per instruction ----------------
// Half-wave h=lane>>5 owns edge parity h; lane holds 4 features (uint2 = 4 bf16)
// -> each gather instr fetches 512 B covering 2 edges; unroll 8 => 16 edges in
// flight per wave. Cross-half combine via shfl_xor(32).

__global__ __launch_bounds__(256) void aggregate_kernel(
    const uint2* __restrict__ Mbf2, const float4* __restrict__ Mself4,
    const int* __restrict__ row_ptr, const float2* __restrict__ meta,
    float4* __restrict__ out4, bf16x4* __restrict__ stbf4) {
    int wid = (blockIdx.x * 256 + threadIdx.x) >> 6;   // node id (2500*4 = NN)
    int lane = threadIdx.x & 63;
    int h = lane >> 5, l5 = lane & 31;
    int beg = row_ptr[wid], end = row_ptr[wid + 1];
    float a0 = 0.f, a1 = 0.f, a2 = 0.f, a3 = 0.f;
    for (int j = beg; j < end; j += 16) {
        float2 m[8];
#pragma unroll
        for (int u = 0; u < 8; u++) {
            int jj = j + 2 * u + h;
            m[u] = (jj < end) ? meta[jj] : make_float2(__int_as_float(0), 0.f);
        }
        uint2 g[8];
#pragma unroll
        for (int u = 0; u < 8; u++)
            g[u] = Mbf2[(size_t)__float_as_int(m[u].x) * 32 + l5];  // 512 B/instr
#pragma unroll
        for (int u = 0; u < 8; u++) {
            float w = m[u].y;
            a0 = fmaf(w, __uint_as_float(g[u].x << 16), a0);
            a1 = fmaf(w, __uint_as_float(g[u].x & 0xFFFF0000u), a1);
            a2 = fmaf(w, __uint_as_float(g[u].y << 16), a2);
            a3 = fmaf(w, __uint_as_float(g[u].y & 0xFFFF0000u), a3);
        }
    }
    a0 += __shfl_xor(a0, 32);
    a1 += __shfl_xor(a1, 32);
    a2 += __shfl_xor(a2, 32);
    a3 += __shfl_xor(a3, 32);
    if (h == 0) {   // lanes 0..31: features 4*l5..4*l5+3, canonical
        float4 sv = Mself4[(size_t)wid * 32 + l5];
        float4 r;
        r.x = fmaxf(a0 + sv.x, 0.f);
        r.y = fmaxf(a1 + sv.y, 0.f);
        r.z = fmaxf(a2 + sv.z, 0.f);
        r.w = fmaxf(a3 + sv.w, 0.f);
        out4[(size_t)wid * 32 + l5] = r;               // graded f32 stacked slice
        bf16x4 hb;
        hb[0] = (__bf16)r.x;
        hb[1] = (__bf16)r.y;
        hb[2] = (__bf16)r.z;
        hb[3] = (__bf16)r.w;
        stbf4[(size_t)wid * 32 + l5] = hb;             // bf16 copy for MFMA consumers
    }
}

// ---------------- fused scoring (MFMA) + softmax + weighted sum ----------------

__global__ __launch_bounds__(256) void score_finalize_mfma(
    const __bf16* __restrict__ stbf, const float* __restrict__ st,
    const __bf16* __restrict__ Wt1, const float* __restrict__ b1,
    const float* __restrict__ w2, const float* __restrict__ b2,
    float* __restrict__ out, float* __restrict__ lw_out) {
    __shared__ __align__(16) __bf16 Wl[D * WS];   // 34816 B
    __shared__ float sc_l[3][64];
    __shared__ float lw_l[3][64];
    int t = threadIdx.x;
    int wid = t >> 6, lane = t & 63;
    int m16 = lane & 15, q = lane >> 4;
    int row0 = blockIdx.x * 64;

    for (int c = wid; c < WCHUNKS; c += 4)
        async_copy16((const char*)Wt1 + c * 1024 + lane * 16,
                     (char*)&Wl[0] + c * 1024 + lane * 16);
    __syncthreads();

    int arow = min(row0 + wid * 16 + m16, NN - 1);
    float bb = b2[0];

    for (int l = 0; l < 3; l++) {
        const __bf16* A = stbf + (size_t)l * NF;
        f32x4 acc[8];
#pragma unroll
        for (int ct = 0; ct < 8; ct++) acc[ct] = (f32x4){0.f, 0.f, 0.f, 0.f};
#pragma unroll
        for (int kk = 0; kk < 4; kk++) {
            bf16x8 a = *(const bf16x8*)&A[(size_t)arow * D + kk * 32 + q * 8];
#pragma unroll
            for (int ct = 0; ct < 8; ct++) {
                bf16x8 b = *(const bf16x8*)&Wl[(ct * 16 + m16) * WS + kk * 32 + q * 8];
                acc[ct] = __builtin_amdgcn_mfma_f32_16x16x32_bf16(a, b, acc[ct], 0, 0, 0);
            }
        }
        float p[4] = {0.f, 0.f, 0.f, 0.f};
#pragma unroll
        for (int ct = 0; ct < 8; ct++) {
            float bv = b1[ct * 16 + m16];
            float wv = w2[ct * 16 + m16];
#pragma unroll
            for (int r = 0; r < 4; r++) p[r] += fmaxf(acc[ct][r] + bv, 0.f) * wv;
        }
#pragma unroll
        for (int r = 0; r < 4; r++) {
#pragma unroll
            for (int off = 1; off < 16; off <<= 1) p[r] += __shfl_xor(p[r], off);
            if (m16 == 0) sc_l[l][wid * 16 + q * 4 + r] = p[r] + bb;
        }
    }
    __syncthreads();

    if (t < 64) {   // per-row softmax over layers
        int row = row0 + t;
        float s0 = sc_l[0][t], s1 = sc_l[1][t], s2 = sc_l[2][t];
        float m = fmaxf(s0, fmaxf(s1, s2));
        float e0 = expf(s0 - m), e1 = expf(s1 - m), e2 = expf(s2 - m);
        float inv = 1.f / (e0 + e1 + e2);
        lw_l[0][t] = e0 * inv;
        lw_l[1][t] = e1 * inv;
        lw_l[2][t] = e2 * inv;
        if (row < NN) {
            lw_out[row] = e0 * inv;
            lw_out[NN + row] = e1 * inv;
            lw_out[2 * NN + row] = e2 * inv;
        }
    }
    __syncthreads();

    // weighted sum over f32 stacked (64 rows x 32 float4)
    for (int i = t; i < 64 * 32; i += 256) {
        int r = i >> 5, c4 = i & 31;
        int row = row0 + r;
        if (row >= NN) break;
        float4 v0 = ((const float4*)(st + (size_t)row * D))[c4];
        float4 v1 = ((const float4*)(st + (size_t)NF + (size_t)row * D))[c4];
        float4 v2 = ((const float4*)(st + 2 * (size_t)NF + (size_t)row * D))[c4];
        float w0 = lw_l[0][r], w1 = lw_l[1][r], w2v = lw_l[2][r];
        float4 o;
        o.x = w0 * v0.x + w1 * v1.x + w2v * v2.x;
        o.y = w0 * v0.y + w1 * v1.y + w2v * v2.y;
        o.z = w0 * v0.z + w1 * v1.z + w2v * v2.z;
        o.w = w0 * v0.w + w1 * v1.w + w2v * v2.w;
        ((float4*)(out + (size_t)row * D))[c4] = o;
    }
}

extern "C" void kernel_launch(void* const* d_in, const int* in_sizes, int n_in,
                              void* d_out, int out_size, void* d_ws, size_t ws_size,
                              hipStream_t stream) {
    const float* x = (const float*)d_in[0];
    const int* ei = (const int*)d_in[1];
    const float* conf = (const float*)d_in[2];
    const float* msg_W1 = (const float*)d_in[3];
    const float* msg_b1 = (const float*)d_in[4];
    const float* msg_W2 = (const float*)d_in[5];
    const float* msg_b2 = (const float*)d_in[6];
    const float* self_W1 = (const float*)d_in[7];
    const float* self_b1 = (const float*)d_in[8];
    const float* self_W2 = (const float*)d_in[9];
    const float* self_b2 = (const float*)d_in[10];
    const float* score_W1 = (const float*)d_in[11];
    const float* score_b1 = (const float*)d_in[12];
    const float* score_W2 = (const float*)d_in[13];
    const float* score_b2 = (const float*)d_in[14];

    float* out = (float*)d_out;                 // [NN,D]
    float* out_stacked = out + NF;              // [3,NN,D]  (canonical f32, graded)
    float* out_lw = out + 4 * (size_t)NF;       // [3,NN]

    float* w = (float*)d_ws;
    float* Mself = w;                              // NF f32
    float2* meta = (float2*)(w + (size_t)NF);      // NE x {src, weight}
    __bf16* xbf = (__bf16*)(meta + NE);            // NF bf16
    __bf16* stbf = xbf + (size_t)NF;               // 3*NF bf16 (per-layer stacked)
    __bf16* Mbf = stbf + 3 * (size_t)NF;           // NF bf16 (msg MLP out, gather set)
    __bf16* wt = Mbf + (size_t)NF;                 // 13 * D * WS bf16
    int* row_ptr = (int*)(wt + 13 * (size_t)D * WS);  // NN+1
    int* cnt = row_ptr + NN + 1;                   // NN
    int* cursor = cnt + NN;                        // NN

    const size_t MAT = (size_t)D * WS;
    const int GE = (NE + 255) / 256;  // 2500
    const int GN = (NN + 255) / 256;  // 40
    const int GB32 = (NN + 31) / 32;  // 313
    const int GB64 = (NN + 63) / 64;  // 157

    zero_cnt_kernel<<<GN, 256, 0, stream>>>(cnt);
    hist_kernel<<<GE, 256, 0, stream>>>(ei, cnt);
    scan_kernel<<<1, 256, 0, stream>>>(cnt, row_ptr, cursor);
    scatter_kernel<<<GE, 256, 0, stream>>>(ei, conf, cursor, meta);
    cvt_x_kernel<<<NF / 512, 256, 0, stream>>>((const float2*)x, (bf16x2*)xbf);
    prep_wt_kernel<<<13, 256, 0, stream>>>(msg_W1, msg_W2, self_W1, self_W2, score_W1, wt);

    for (int l = 0; l < 3; l++) {
        const __bf16* a_in = (l == 0) ? xbf : stbf + (size_t)(l - 1) * NF;
        mlp_pair_mfma<<<dim3(GB32, 2), 128, 0, stream>>>(
            a_in,
            wt + (size_t)l * MAT, msg_b1 + (size_t)l * D,
            wt + (size_t)(3 + l) * MAT, msg_b2 + (size_t)l * D, Mbf,
            wt + (size_t)(6 + l) * MAT, self_b1 + (size_t)l * D,
            wt + (size_t)(9 + l) * MAT, self_b2 + (size_t)l * D, Mself);
        aggregate_kernel<<<NN / 4, 256, 0, stream>>>(
            (const uint2*)Mbf, (const float4*)Mself, row_ptr, meta,
            (float4*)(out_stacked + (size_t)l * NF),
            (bf16x4*)(stbf + (size_t)l * NF));
    }

    score_finalize_mfma<<<GB64, 256, 0, stream>>>(
        stbf, out_stacked, wt + 12 * MAT, score_b1, score_W2, score_b2, out, out_lw);
}

// Round 9
// 338.271 us; speedup vs baseline: 1.7280x; 1.1401x over previous
//
#include <hip/hip_runtime.h>

#define NN 10000
#define NE 640000
#define D 128
#define NF (NN * D)
#define WS 136   // padded bf16 row stride: 272 B = 16B-aligned, 2-way-free LDS banks
#define WBYTES (D * WS * 2)      // 34816 B per W^T matrix
#define WCHUNKS (WBYTES / 1024)  // 34 async 1KB wave-chunks

typedef __bf16 bf16x8 __attribute__((ext_vector_type(8)));
typedef __bf16 bf16x4 __attribute__((ext_vector_type(4)));
typedef __bf16 bf16x2 __attribute__((ext_vector_type(2)));
typedef float f32x4 __attribute__((ext_vector_type(4)));

// async global->LDS, 16B per lane, 1 KB per wave-call [m97-verified width=16]
__device__ __forceinline__ void async_copy16(const void* g, void* l) {
    __builtin_amdgcn_global_load_lds(
        (const __attribute__((address_space(1))) unsigned int*)g,
        (__attribute__((address_space(3))) unsigned int*)l, 16, 0, 0);
}

// ---------------- fused prep: hist+rank | x->bf16 | W->bf16 transposed ----------------
// blocks [0,2500): histogram of dst + per-edge rank (coalesced store)
// blocks [2500,5000): x -> bf16
// blocks [5000,5013): W -> Wt[n][k] bf16, stride WS
__global__ __launch_bounds__(256) void prep_all_kernel(
    const int* __restrict__ ei, int* __restrict__ cnt, int* __restrict__ rank,
    const float2* __restrict__ x2, bf16x2* __restrict__ xbf,
    const float* __restrict__ mW1, const float* __restrict__ mW2,
    const float* __restrict__ sW1, const float* __restrict__ sW2,
    const float* __restrict__ scW1, __bf16* __restrict__ wt) {
    int b = blockIdx.x;
    if (b < 2500) {
        int e = b * 256 + threadIdx.x;
        rank[e] = atomicAdd(&cnt[ei[NE + e]], 1);   // return is free; store coalesced
    } else if (b < 5000) {
        int i = (b - 2500) * 256 + threadIdx.x;     // NF/2 = 640000
        float2 v = x2[i];
        bf16x2 o;
        o.x = (__bf16)v.x;
        o.y = (__bf16)v.y;
        xbf[i] = o;
    } else {
        int m = b - 5000;  // 0-2 msg_W1, 3-5 msg_W2, 6-8 self_W1, 9-11 self_W2, 12 score_W1
        const float* W = (m < 3)   ? mW1 + (size_t)m * D * D
                       : (m < 6)   ? mW2 + (size_t)(m - 3) * D * D
                       : (m < 9)   ? sW1 + (size_t)(m - 6) * D * D
                       : (m < 12)  ? sW2 + (size_t)(m - 9) * D * D
                                   : scW1;
        __bf16* o = wt + (size_t)m * D * WS;
        for (int i = threadIdx.x; i < D * D; i += 256) {
            int k = i >> 7, n = i & 127;
            o[n * WS + k] = (__bf16)W[i];
        }
    }
}

__global__ void scan_kernel(const int* __restrict__ cnt, int* __restrict__ row_ptr) {
    __shared__ int lds[256];
    int t = threadIdx.x;
    const int CH = (NN + 255) / 256;  // 40
    int base = t * CH;
    int s = 0;
    for (int i = 0; i < CH; i++) {
        int idx = base + i;
        if (idx < NN) s += cnt[idx];
    }
    lds[t] = s;
    __syncthreads();
    for (int off = 1; off < 256; off <<= 1) {
        int v = (t >= off) ? lds[t - off] : 0;
        __syncthreads();
        lds[t] += v;
        __syncthreads();
    }
    int run = (t == 0) ? 0 : lds[t - 1];
    for (int i = 0; i < CH; i++) {
        int idx = base + i;
        if (idx < NN) {
            row_ptr[idx] = run;
            run += cnt[idx];
        }
    }
    if (t == 255) row_ptr[NN] = lds[255];
}

// atomic-free scatter: pos = row_ptr[dst] + rank  (store is fire-and-forget)
__global__ void scatter_kernel(const int* __restrict__ ei, const float* __restrict__ conf,
                               const int* __restrict__ rank, const int* __restrict__ row_ptr,
                               float2* __restrict__ meta) {
    int e = blockIdx.x * 256 + threadIdx.x;
    if (e >= NE) return;
    int s = ei[e];
    int d = ei[NE + e];
    int pos = row_ptr[d] + rank[e];
    meta[pos] = make_float2(__int_as_float(s), expf(-fabsf(conf[s] - conf[d])));
}

// ---------------- fused 2-layer MLP via bf16 MFMA ----------------
// Block = 2 waves x 16 rows. W1^T async-staged; after barrier-1, W2^T's async
// staging is issued and OVERLAPS stage-1 MFMAs (barrier drains all vmcnt, so
// up-front dual staging would serialize). A-frags + biases preloaded to regs.
// blockIdx.y==0: msg -> bf16 out (L2-resident gather set); ==1: self -> f32.

__global__ __launch_bounds__(128) void mlp_pair_mfma(
    const __bf16* __restrict__ Abf,
    const __bf16* __restrict__ Wt1a, const float* __restrict__ b1a,
    const __bf16* __restrict__ Wt2a, const float* __restrict__ b2a, __bf16* __restrict__ Mbf,
    const __bf16* __restrict__ Wt1b, const float* __restrict__ b1b,
    const __bf16* __restrict__ Wt2b, const float* __restrict__ b2b, float* __restrict__ Cself) {
    const __bf16* Wt1 = blockIdx.y ? Wt1b : Wt1a;
    const float* b1 = blockIdx.y ? b1b : b1a;
    const __bf16* Wt2 = blockIdx.y ? Wt2b : Wt2a;
    const float* b2 = blockIdx.y ? b2b : b2a;

    __shared__ __align__(16) __bf16 Wl[2][D * WS];    // 2 x 34816 B
    __shared__ __align__(16) __bf16 Tl[2][16 * WS];   // 4352 B per wave
    int t = threadIdx.x;
    int wid = t >> 6, lane = t & 63;
    int m16 = lane & 15, q = lane >> 4;

    // stage W1^T only (async)
    for (int c = wid; c < WCHUNKS; c += 2)
        async_copy16((const char*)Wt1 + c * 1024 + lane * 16,
                     (char*)&Wl[0][0] + c * 1024 + lane * 16);

    int row0 = blockIdx.x * 32 + wid * 16;
    int arow = min(row0 + m16, NN - 1);   // clamp tail reads; stores are guarded

    // preload A-frags + biases while W1 staging is in flight
    bf16x8 af[4];
#pragma unroll
    for (int kk = 0; kk < 4; kk++) af[kk] = *(const bf16x8*)&Abf[(size_t)arow * D + kk * 32 + q * 8];
    float b1v[8], b2v[8];
#pragma unroll
    for (int ct = 0; ct < 8; ct++) { b1v[ct] = b1[ct * 16 + m16]; b2v[ct] = b2[ct * 16 + m16]; }

    __syncthreads();   // drains W1 staging (and the register preloads)

    // now issue W2^T staging — overlaps stage-1 MFMAs below
    for (int c = wid; c < WCHUNKS; c += 2)
        async_copy16((const char*)Wt2 + c * 1024 + lane * 16,
                     (char*)&Wl[1][0] + c * 1024 + lane * 16);

    // ---- stage 1 ----
    f32x4 acc[8];
#pragma unroll
    for (int ct = 0; ct < 8; ct++) acc[ct] = (f32x4){0.f, 0.f, 0.f, 0.f};
#pragma unroll
    for (int kk = 0; kk < 4; kk++) {
#pragma unroll
        for (int ct = 0; ct < 8; ct++) {
            bf16x8 b = *(const bf16x8*)&Wl[0][(ct * 16 + m16) * WS + kk * 32 + q * 8];
            acc[ct] = __builtin_amdgcn_mfma_f32_16x16x32_bf16(af[kk], b, acc[ct], 0, 0, 0);
        }
    }
#pragma unroll
    for (int ct = 0; ct < 8; ct++) {
#pragma unroll
        for (int r = 0; r < 4; r++) {
            float v = fmaxf(acc[ct][r] + b1v[ct], 0.f);
            Tl[wid][(q * 4 + r) * WS + ct * 16 + m16] = (__bf16)v;
        }
    }
    __syncthreads();   // drains W2 staging; T is wave-private (no hazard)

    // ---- stage 2 ----
#pragma unroll
    for (int ct = 0; ct < 8; ct++) acc[ct] = (f32x4){0.f, 0.f, 0.f, 0.f};
#pragma unroll
    for (int kk = 0; kk < 4; kk++) {
        bf16x8 a = *(const bf16x8*)&Tl[wid][m16 * WS + kk * 32 + q * 8];
#pragma unroll
        for (int ct = 0; ct < 8; ct++) {
            bf16x8 b = *(const bf16x8*)&Wl[1][(ct * 16 + m16) * WS + kk * 32 + q * 8];
            acc[ct] = __builtin_amdgcn_mfma_f32_16x16x32_bf16(a, b, acc[ct], 0, 0, 0);
        }
    }
    if (blockIdx.y == 0) {   // msg -> bf16 (L2-resident gather set)
#pragma unroll
        for (int ct = 0; ct < 8; ct++) {
#pragma unroll
            for (int r = 0; r < 4; r++) {
                int row = row0 + q * 4 + r;
                if (row < NN) Mbf[(size_t)row * D + ct * 16 + m16] = (__bf16)(acc[ct][r] + b2v[ct]);
            }
        }
    } else {                 // self -> f32 (streamed once, keep precision)
#pragma unroll
        for (int ct = 0; ct < 8; ct++) {
#pragma unroll
            for (int r = 0; r < 4; r++) {
                int row = row0 + q * 4 + r;
                if (row < NN) Cself[(size_t)row * D + ct * 16 + m16] = acc[ct][r] + b2v[ct];
            }
        }
    }
}

// ---------------- CSR aggregate: one WAVE per node, up to 32 edges in flight ----------------
// Half-wave h owns edge parity h; lane holds 4 features (uint2). Guarded loads
// are exec-masked -> ragged tails issue no wasted line-requests.

__global__ __launch_bounds__(256) void aggregate_kernel(
    const uint2* __restrict__ Mbf2, const float4* __restrict__ Mself4,
    const int* __restrict__ row_ptr, const float2* __restrict__ meta,
    float4* __restrict__ out4, bf16x4* __restrict__ stbf4) {
    int wid = (blockIdx.x * 256 + threadIdx.x) >> 6;   // node id (2500*4 = NN)
    int lane = threadIdx.x & 63;
    int h = lane >> 5, l5 = lane & 31;
    int beg = row_ptr[wid], end = row_ptr[wid + 1];
    float a0 = 0.f, a1 = 0.f, a2 = 0.f, a3 = 0.f;
    for (int j = beg; j < end; j += 32) {
        float2 m[16];
        uint2 g[16];
#pragma unroll
        for (int u = 0; u < 16; u++) {
            int jj = j + 2 * u + h;
            m[u] = make_float2(__int_as_float(0), 0.f);
            if (jj < end) m[u] = meta[jj];
        }
#pragma unroll
        for (int u = 0; u < 16; u++) {
            g[u] = make_uint2(0u, 0u);
            if (j + 2 * u + h < end) g[u] = Mbf2[(size_t)__float_as_int(m[u].x) * 32 + l5];
        }
#pragma unroll
        for (int u = 0; u < 16; u++) {
            float w = m[u].y;
            a0 = fmaf(w, __uint_as_float(g[u].x << 16), a0);
            a1 = fmaf(w, __uint_as_float(g[u].x & 0xFFFF0000u), a1);
            a2 = fmaf(w, __uint_as_float(g[u].y << 16), a2);
            a3 = fmaf(w, __uint_as_float(g[u].y & 0xFFFF0000u), a3);
        }
    }
    a0 += __shfl_xor(a0, 32);
    a1 += __shfl_xor(a1, 32);
    a2 += __shfl_xor(a2, 32);
    a3 += __shfl_xor(a3, 32);
    if (h == 0) {   // lanes 0..31: features 4*l5..4*l5+3, canonical
        float4 sv = Mself4[(size_t)wid * 32 + l5];
        float4 r;
        r.x = fmaxf(a0 + sv.x, 0.f);
        r.y = fmaxf(a1 + sv.y, 0.f);
        r.z = fmaxf(a2 + sv.z, 0.f);
        r.w = fmaxf(a3 + sv.w, 0.f);
        out4[(size_t)wid * 32 + l5] = r;               // graded f32 stacked slice
        bf16x4 hb;
        hb[0] = (__bf16)r.x;
        hb[1] = (__bf16)r.y;
        hb[2] = (__bf16)r.z;
        hb[3] = (__bf16)r.w;
        stbf4[(size_t)wid * 32 + l5] = hb;             // bf16 copy for MFMA consumers
    }
}

// ---------------- fused scoring (MFMA) + softmax + weighted sum ----------------

__global__ __launch_bounds__(256) void score_finalize_mfma(
    const __bf16* __restrict__ stbf, const float* __restrict__ st,
    const __bf16* __restrict__ Wt1, const float* __restrict__ b1,
    const float* __restrict__ w2, const float* __restrict__ b2,
    float* __restrict__ out, float* __restrict__ lw_out) {
    __shared__ __align__(16) __bf16 Wl[D * WS];   // 34816 B
    __shared__ float sc_l[3][64];
    __shared__ float lw_l[3][64];
    int t = threadIdx.x;
    int wid = t >> 6, lane = t & 63;
    int m16 = lane & 15, q = lane >> 4;
    int row0 = blockIdx.x * 64;

    for (int c = wid; c < WCHUNKS; c += 4)
        async_copy16((const char*)Wt1 + c * 1024 + lane * 16,
                     (char*)&Wl[0] + c * 1024 + lane * 16);
    __syncthreads();

    int arow = min(row0 + wid * 16 + m16, NN - 1);
    float bb = b2[0];

    for (int l = 0; l < 3; l++) {
        const __bf16* A = stbf + (size_t)l * NF;
        f32x4 acc[8];
#pragma unroll
        for (int ct = 0; ct < 8; ct++) acc[ct] = (f32x4){0.f, 0.f, 0.f, 0.f};
#pragma unroll
        for (int kk = 0; kk < 4; kk++) {
            bf16x8 a = *(const bf16x8*)&A[(size_t)arow * D + kk * 32 + q * 8];
#pragma unroll
            for (int ct = 0; ct < 8; ct++) {
                bf16x8 b = *(const bf16x8*)&Wl[(ct * 16 + m16) * WS + kk * 32 + q * 8];
                acc[ct] = __builtin_amdgcn_mfma_f32_16x16x32_bf16(a, b, acc[ct], 0, 0, 0);
            }
        }
        float p[4] = {0.f, 0.f, 0.f, 0.f};
#pragma unroll
        for (int ct = 0; ct < 8; ct++) {
            float bv = b1[ct * 16 + m16];
            float wv = w2[ct * 16 + m16];
#pragma unroll
            for (int r = 0; r < 4; r++) p[r] += fmaxf(acc[ct][r] + bv, 0.f) * wv;
        }
#pragma unroll
        for (int r = 0; r < 4; r++) {
#pragma unroll
            for (int off = 1; off < 16; off <<= 1) p[r] += __shfl_xor(p[r], off);
            if (m16 == 0) sc_l[l][wid * 16 + q * 4 + r] = p[r] + bb;
        }
    }
    __syncthreads();

    if (t < 64) {   // per-row softmax over layers
        int row = row0 + t;
        float s0 = sc_l[0][t], s1 = sc_l[1][t], s2 = sc_l[2][t];
        float m = fmaxf(s0, fmaxf(s1, s2));
        float e0 = expf(s0 - m), e1 = expf(s1 - m), e2 = expf(s2 - m);
        float inv = 1.f / (e0 + e1 + e2);
        lw_l[0][t] = e0 * inv;
        lw_l[1][t] = e1 * inv;
        lw_l[2][t] = e2 * inv;
        if (row < NN) {
            lw_out[row] = e0 * inv;
            lw_out[NN + row] = e1 * inv;
            lw_out[2 * NN + row] = e2 * inv;
        }
    }
    __syncthreads();

    // weighted sum over f32 stacked (64 rows x 32 float4)
    for (int i = t; i < 64 * 32; i += 256) {
        int r = i >> 5, c4 = i & 31;
        int row = row0 + r;
        if (row >= NN) break;
        float4 v0 = ((const float4*)(st + (size_t)row * D))[c4];
        float4 v1 = ((const float4*)(st + (size_t)NF + (size_t)row * D))[c4];
        float4 v2 = ((const float4*)(st + 2 * (size_t)NF + (size_t)row * D))[c4];
        float w0 = lw_l[0][r], w1 = lw_l[1][r], w2v = lw_l[2][r];
        float4 o;
        o.x = w0 * v0.x + w1 * v1.x + w2v * v2.x;
        o.y = w0 * v0.y + w1 * v1.y + w2v * v2.y;
        o.z = w0 * v0.z + w1 * v1.z + w2v * v2.z;
        o.w = w0 * v0.w + w1 * v1.w + w2v * v2.w;
        ((float4*)(out + (size_t)row * D))[c4] = o;
    }
}

extern "C" void kernel_launch(void* const* d_in, const int* in_sizes, int n_in,
                              void* d_out, int out_size, void* d_ws, size_t ws_size,
                              hipStream_t stream) {
    const float* x = (const float*)d_in[0];
    const int* ei = (const int*)d_in[1];
    const float* conf = (const float*)d_in[2];
    const float* msg_W1 = (const float*)d_in[3];
    const float* msg_b1 = (const float*)d_in[4];
    const float* msg_W2 = (const float*)d_in[5];
    const float* msg_b2 = (const float*)d_in[6];
    const float* self_W1 = (const float*)d_in[7];
    const float* self_b1 = (const float*)d_in[8];
    const float* self_W2 = (const float*)d_in[9];
    const float* self_b2 = (const float*)d_in[10];
    const float* score_W1 = (const float*)d_in[11];
    const float* score_b1 = (const float*)d_in[12];
    const float* score_W2 = (const float*)d_in[13];
    const float* score_b2 = (const float*)d_in[14];

    float* out = (float*)d_out;                 // [NN,D]
    float* out_stacked = out + NF;              // [3,NN,D]  (canonical f32, graded)
    float* out_lw = out + 4 * (size_t)NF;       // [3,NN]

    float* w = (float*)d_ws;
    float* Mself = w;                              // NF f32
    float2* meta = (float2*)(w + (size_t)NF);      // NE x {src, weight}
    __bf16* xbf = (__bf16*)(meta + NE);            // NF bf16
    __bf16* stbf = xbf + (size_t)NF;               // 3*NF bf16 (per-layer stacked)
    __bf16* Mbf = stbf + 3 * (size_t)NF;           // NF bf16 (msg MLP out, gather set)
    __bf16* wt = Mbf + (size_t)NF;                 // 13 * D * WS bf16
    int* rank = (int*)(wt + 13 * (size_t)D * WS);  // NE
    int* row_ptr = rank + NE;                      // NN+1
    int* cnt = row_ptr + NN + 1;                   // NN

    const size_t MAT = (size_t)D * WS;
    const int GE = (NE + 255) / 256;  // 2500
    const int GB32 = (NN + 31) / 32;  // 313
    const int GB64 = (NN + 63) / 64;  // 157

    hipMemsetAsync(cnt, 0, NN * sizeof(int), stream);
    prep_all_kernel<<<5013, 256, 0, stream>>>(ei, cnt, rank, (const float2*)x, (bf16x2*)xbf,
                                              msg_W1, msg_W2, self_W1, self_W2, score_W1, wt);
    scan_kernel<<<1, 256, 0, stream>>>(cnt, row_ptr);
    scatter_kernel<<<GE, 256, 0, stream>>>(ei, conf, rank, row_ptr, meta);

    for (int l = 0; l < 3; l++) {
        const __bf16* a_in = (l == 0) ? xbf : stbf + (size_t)(l - 1) * NF;
        mlp_pair_mfma<<<dim3(GB32, 2), 128, 0, stream>>>(
            a_in,
            wt + (size_t)l * MAT, msg_b1 + (size_t)l * D,
            wt + (size_t)(3 + l) * MAT, msg_b2 + (size_t)l * D, Mbf,
            wt + (size_t)(6 + l) * MAT, self_b1 + (size_t)l * D,
            wt + (size_t)(9 + l) * MAT, self_b2 + (size_t)l * D, Mself);
        aggregate_kernel<<<NN / 4, 256, 0, stream>>>(
            (const uint2*)Mbf, (const float4*)Mself, row_ptr, meta,
            (float4*)(out_stacked + (size_t)l * NF),
            (bf16x4*)(stbf + (size_t)l * NF));
    }

    score_finalize_mfma<<<GB64, 256, 0, stream>>>(
        stbf, out_stacked, wt + 12 * MAT, score_b1, score_W2, score_b2, out, out_lw);
}

// Round 10
// 284.863 us; speedup vs baseline: 2.0519x; 1.1875x over previous
//
#include <hip/hip_runtime.h>

#define NN 10000
#define NE 640000
#define D 128
#define NF (NN * D)
#define WS 136   // padded bf16 row stride: 272 B = 16B-aligned, 2-way-free LDS banks
#define WBYTES (D * WS * 2)      // 34816 B per W^T matrix
#define WCHUNKS (WBYTES / 1024)  // 34 async 1KB wave-chunks
#define NBLK 100                 // hist blocks
#define EPB (NE / NBLK)          // 6400 edges per hist block (25 iters of 256)

typedef __bf16 bf16x8 __attribute__((ext_vector_type(8)));
typedef __bf16 bf16x2 __attribute__((ext_vector_type(2)));
typedef float f32x4 __attribute__((ext_vector_type(4)));

// async global->LDS, 16B per lane, 1 KB per wave-call [m97-verified width=16]
__device__ __forceinline__ void async_copy16(const void* g, void* l) {
    __builtin_amdgcn_global_load_lds(
        (const __attribute__((address_space(1))) unsigned int*)g,
        (__attribute__((address_space(3))) unsigned int*)l, 16, 0, 0);
}

// ---------------- CSR build: LDS histogram (no global atomics) ----------------

__global__ __launch_bounds__(256) void hist_lds_kernel(const int* __restrict__ ei,
                                                       int* __restrict__ cnt_blk,
                                                       int* __restrict__ local_rank) {
    __shared__ int hist[NN];   // 40 KB
    int b = blockIdx.x, t = threadIdx.x;
    for (int i = t; i < NN; i += 256) hist[i] = 0;
    __syncthreads();
    int base = b * EPB;
#pragma unroll 1
    for (int i = 0; i < EPB / 256; i++) {
        int e = base + i * 256 + t;
        int d = ei[NE + e];
        local_rank[e] = atomicAdd(&hist[d], 1);   // LDS atomic: fast, block-local
    }
    __syncthreads();
    for (int i = t; i < NN; i += 256) cnt_blk[b * NN + i] = hist[i];
}

// per-node prefix over blocks (in place) + total count; fully coalesced
__global__ void colsum_kernel(int* __restrict__ cnt_blk, int* __restrict__ cnt) {
    int n = blockIdx.x * 256 + threadIdx.x;
    if (n >= NN) return;
    int acc = 0;
#pragma unroll 4
    for (int b = 0; b < NBLK; b++) {
        int v = cnt_blk[b * NN + n];
        cnt_blk[b * NN + n] = acc;   // exclusive block-prefix replaces count
        acc += v;
    }
    cnt[n] = acc;
}

__global__ void scan_kernel(const int* __restrict__ cnt, int* __restrict__ row_ptr) {
    __shared__ int lds[256];
    int t = threadIdx.x;
    const int CH = (NN + 255) / 256;  // 40
    int base = t * CH;
    int s = 0;
    for (int i = 0; i < CH; i++) {
        int idx = base + i;
        if (idx < NN) s += cnt[idx];
    }
    lds[t] = s;
    __syncthreads();
    for (int off = 1; off < 256; off <<= 1) {
        int v = (t >= off) ? lds[t - off] : 0;
        __syncthreads();
        lds[t] += v;
        __syncthreads();
    }
    int run = (t == 0) ? 0 : lds[t - 1];
    for (int i = 0; i < CH; i++) {
        int idx = base + i;
        if (idx < NN) {
            row_ptr[idx] = run;
            run += cnt[idx];
        }
    }
    if (t == 255) row_ptr[NN] = lds[255];
}

// atomic-free scatter: pos = row_ptr[dst] + block_prefix + local_rank
__global__ void scatter_kernel(const int* __restrict__ ei, const float* __restrict__ conf,
                               const int* __restrict__ local_rank,
                               const int* __restrict__ cnt_blk,
                               const int* __restrict__ row_ptr, float2* __restrict__ meta) {
    int e = blockIdx.x * 256 + threadIdx.x;
    if (e >= NE) return;
    int s = ei[e];
    int d = ei[NE + e];
    int blk = e / EPB;   // const divide -> magic mul
    int pos = row_ptr[d] + cnt_blk[blk * NN + d] + local_rank[e];
    meta[pos] = make_float2(__int_as_float(s), expf(-fabsf(conf[s] - conf[d])));
}

// ---------------- prep: x -> bf16 | W -> bf16 transposed ----------------
__global__ __launch_bounds__(256) void prep_all_kernel(
    const float2* __restrict__ x2, bf16x2* __restrict__ xbf,
    const float* __restrict__ mW1, const float* __restrict__ mW2,
    const float* __restrict__ sW1, const float* __restrict__ sW2,
    const float* __restrict__ scW1, __bf16* __restrict__ wt) {
    int b = blockIdx.x;
    if (b < 2500) {
        int i = b * 256 + threadIdx.x;     // NF/2 = 640000
        float2 v = x2[i];
        bf16x2 o;
        o.x = (__bf16)v.x;
        o.y = (__bf16)v.y;
        xbf[i] = o;
    } else {
        int m = b - 2500;  // 0-2 msg_W1, 3-5 msg_W2, 6-8 self_W1, 9-11 self_W2, 12 score_W1
        const float* W = (m < 3)   ? mW1 + (size_t)m * D * D
                       : (m < 6)   ? mW2 + (size_t)(m - 3) * D * D
                       : (m < 9)   ? sW1 + (size_t)(m - 6) * D * D
                       : (m < 12)  ? sW2 + (size_t)(m - 9) * D * D
                                   : scW1;
        __bf16* o = wt + (size_t)m * D * WS;
        for (int i = threadIdx.x; i < D * D; i += 256) {
            int k = i >> 7, n = i & 127;
            o[n * WS + k] = (__bf16)W[i];
        }
    }
}

// ---------------- fused 2-layer MLP via bf16 MFMA ----------------
// Block = 2 waves x 16 rows. W1^T async-staged; W2^T staging issued after
// barrier-1 so it overlaps stage-1 MFMAs. A-frags + biases preloaded.
// blockIdx.y==0: msg -> bf16 out (L2-resident gather set); ==1: self -> f32.

__global__ __launch_bounds__(128) void mlp_pair_mfma(
    const __bf16* __restrict__ Abf,
    const __bf16* __restrict__ Wt1a, const float* __restrict__ b1a,
    const __bf16* __restrict__ Wt2a, const float* __restrict__ b2a, __bf16* __restrict__ Mbf,
    const __bf16* __restrict__ Wt1b, const float* __restrict__ b1b,
    const __bf16* __restrict__ Wt2b, const float* __restrict__ b2b, float* __restrict__ Cself) {
    const __bf16* Wt1 = blockIdx.y ? Wt1b : Wt1a;
    const float* b1 = blockIdx.y ? b1b : b1a;
    const __bf16* Wt2 = blockIdx.y ? Wt2b : Wt2a;
    const float* b2 = blockIdx.y ? b2b : b2a;

    __shared__ __align__(16) __bf16 Wl[2][D * WS];    // 2 x 34816 B
    __shared__ __align__(16) __bf16 Tl[2][16 * WS];   // 4352 B per wave
    int t = threadIdx.x;
    int wid = t >> 6, lane = t & 63;
    int m16 = lane & 15, q = lane >> 4;

    for (int c = wid; c < WCHUNKS; c += 2)
        async_copy16((const char*)Wt1 + c * 1024 + lane * 16,
                     (char*)&Wl[0][0] + c * 1024 + lane * 16);

    int row0 = blockIdx.x * 32 + wid * 16;
    int arow = min(row0 + m16, NN - 1);   // clamp tail reads; stores are guarded

    bf16x8 af[4];
#pragma unroll
    for (int kk = 0; kk < 4; kk++) af[kk] = *(const bf16x8*)&Abf[(size_t)arow * D + kk * 32 + q * 8];
    float b1v[8], b2v[8];
#pragma unroll
    for (int ct = 0; ct < 8; ct++) { b1v[ct] = b1[ct * 16 + m16]; b2v[ct] = b2[ct * 16 + m16]; }

    __syncthreads();   // drains W1 staging

    for (int c = wid; c < WCHUNKS; c += 2)   // W2 staging overlaps stage-1 MFMAs
        async_copy16((const char*)Wt2 + c * 1024 + lane * 16,
                     (char*)&Wl[1][0] + c * 1024 + lane * 16);

    // ---- stage 1 ----
    f32x4 acc[8];
#pragma unroll
    for (int ct = 0; ct < 8; ct++) acc[ct] = (f32x4){0.f, 0.f, 0.f, 0.f};
#pragma unroll
    for (int kk = 0; kk < 4; kk++) {
#pragma unroll
        for (int ct = 0; ct < 8; ct++) {
            bf16x8 b = *(const bf16x8*)&Wl[0][(ct * 16 + m16) * WS + kk * 32 + q * 8];
            acc[ct] = __builtin_amdgcn_mfma_f32_16x16x32_bf16(af[kk], b, acc[ct], 0, 0, 0);
        }
    }
#pragma unroll
    for (int ct = 0; ct < 8; ct++) {
#pragma unroll
        for (int r = 0; r < 4; r++) {
            float v = fmaxf(acc[ct][r] + b1v[ct], 0.f);
            Tl[wid][(q * 4 + r) * WS + ct * 16 + m16] = (__bf16)v;
        }
    }
    __syncthreads();   // drains W2 staging; T is wave-private

    // ---- stage 2 ----
#pragma unroll
    for (int ct = 0; ct < 8; ct++) acc[ct] = (f32x4){0.f, 0.f, 0.f, 0.f};
#pragma unroll
    for (int kk = 0; kk < 4; kk++) {
        bf16x8 a = *(const bf16x8*)&Tl[wid][m16 * WS + kk * 32 + q * 8];
#pragma unroll
        for (int ct = 0; ct < 8; ct++) {
            bf16x8 b = *(const bf16x8*)&Wl[1][(ct * 16 + m16) * WS + kk * 32 + q * 8];
            acc[ct] = __builtin_amdgcn_mfma_f32_16x16x32_bf16(a, b, acc[ct], 0, 0, 0);
        }
    }
    if (blockIdx.y == 0) {
#pragma unroll
        for (int ct = 0; ct < 8; ct++) {
#pragma unroll
            for (int r = 0; r < 4; r++) {
                int row = row0 + q * 4 + r;
                if (row < NN) Mbf[(size_t)row * D + ct * 16 + m16] = (__bf16)(acc[ct][r] + b2v[ct]);
            }
        }
    } else {
#pragma unroll
        for (int ct = 0; ct < 8; ct++) {
#pragma unroll
            for (int r = 0; r < 4; r++) {
                int row = row0 + q * 4 + r;
                if (row < NN) Cself[(size_t)row * D + ct * 16 + m16] = acc[ct][r] + b2v[ct];
            }
        }
    }
}

// ---------------- CSR aggregate: one WAVE per node, quarter-wave gathers ----------------
// Quarter q owns edge j+4u+q; lane holds 8 features (uint4 = 16 B) -> 4 edges
// per gather instruction, unroll 8 => 32 edges in flight with half the
// instructions of the half-wave scheme. Combine via shfl_xor(16), (32).

__global__ __launch_bounds__(256) void aggregate_kernel(
    const uint4* __restrict__ Mbf4, const float4* __restrict__ Mself4,
    const int* __restrict__ row_ptr, const float2* __restrict__ meta,
    float4* __restrict__ out4, bf16x8* __restrict__ stbf8) {
    int wid = (blockIdx.x * 256 + threadIdx.x) >> 6;   // node id (2500*4 = NN)
    int lane = threadIdx.x & 63;
    int q = lane >> 4, l4 = lane & 15;
    int beg = row_ptr[wid], end = row_ptr[wid + 1];
    float a[8] = {0.f, 0.f, 0.f, 0.f, 0.f, 0.f, 0.f, 0.f};
    for (int j = beg; j < end; j += 32) {
        float2 m[8];
        uint4 g[8];
#pragma unroll
        for (int u = 0; u < 8; u++) {
            int jj = j + 4 * u + q;
            m[u] = make_float2(__int_as_float(0), 0.f);
            if (jj < end) m[u] = meta[jj];   // 16 lanes same addr -> broadcast
        }
#pragma unroll
        for (int u = 0; u < 8; u++) {
            g[u] = make_uint4(0u, 0u, 0u, 0u);
            if (j + 4 * u + q < end) g[u] = Mbf4[(size_t)__float_as_int(m[u].x) * 16 + l4];
        }
#pragma unroll
        for (int u = 0; u < 8; u++) {
            float w = m[u].y;
            a[0] = fmaf(w, __uint_as_float(g[u].x << 16), a[0]);
            a[1] = fmaf(w, __uint_as_float(g[u].x & 0xFFFF0000u), a[1]);
            a[2] = fmaf(w, __uint_as_float(g[u].y << 16), a[2]);
            a[3] = fmaf(w, __uint_as_float(g[u].y & 0xFFFF0000u), a[3]);
            a[4] = fmaf(w, __uint_as_float(g[u].z << 16), a[4]);
            a[5] = fmaf(w, __uint_as_float(g[u].z & 0xFFFF0000u), a[5]);
            a[6] = fmaf(w, __uint_as_float(g[u].w << 16), a[6]);
            a[7] = fmaf(w, __uint_as_float(g[u].w & 0xFFFF0000u), a[7]);
        }
    }
#pragma unroll
    for (int i = 0; i < 8; i++) {
        a[i] += __shfl_xor(a[i], 16);
        a[i] += __shfl_xor(a[i], 32);
    }
    if (q == 0) {   // lanes 0..15: features 8*l4 .. 8*l4+7, canonical
        float4 sv0 = Mself4[(size_t)wid * 32 + 2 * l4];
        float4 sv1 = Mself4[(size_t)wid * 32 + 2 * l4 + 1];
        float4 r0, r1;
        r0.x = fmaxf(a[0] + sv0.x, 0.f);
        r0.y = fmaxf(a[1] + sv0.y, 0.f);
        r0.z = fmaxf(a[2] + sv0.z, 0.f);
        r0.w = fmaxf(a[3] + sv0.w, 0.f);
        r1.x = fmaxf(a[4] + sv1.x, 0.f);
        r1.y = fmaxf(a[5] + sv1.y, 0.f);
        r1.z = fmaxf(a[6] + sv1.z, 0.f);
        r1.w = fmaxf(a[7] + sv1.w, 0.f);
        out4[(size_t)wid * 32 + 2 * l4] = r0;          // graded f32 stacked slice
        out4[(size_t)wid * 32 + 2 * l4 + 1] = r1;
        bf16x8 hb;
        hb[0] = (__bf16)r0.x; hb[1] = (__bf16)r0.y;
        hb[2] = (__bf16)r0.z; hb[3] = (__bf16)r0.w;
        hb[4] = (__bf16)r1.x; hb[5] = (__bf16)r1.y;
        hb[6] = (__bf16)r1.z; hb[7] = (__bf16)r1.w;
        stbf8[(size_t)wid * 16 + l4] = hb;             // bf16 copy for MFMA consumers
    }
}

// ---------------- fused scoring (MFMA) + softmax + weighted sum ----------------

__global__ __launch_bounds__(256) void score_finalize_mfma(
    const __bf16* __restrict__ stbf, const float* __restrict__ st,
    const __bf16* __restrict__ Wt1, const float* __restrict__ b1,
    const float* __restrict__ w2, const float* __restrict__ b2,
    float* __restrict__ out, float* __restrict__ lw_out) {
    __shared__ __align__(16) __bf16 Wl[D * WS];   // 34816 B
    __shared__ float sc_l[3][64];
    __shared__ float lw_l[3][64];
    int t = threadIdx.x;
    int wid = t >> 6, lane = t & 63;
    int m16 = lane & 15, q = lane >> 4;
    int row0 = blockIdx.x * 64;

    for (int c = wid; c < WCHUNKS; c += 4)
        async_copy16((const char*)Wt1 + c * 1024 + lane * 16,
                     (char*)&Wl[0] + c * 1024 + lane * 16);
    __syncthreads();

    int arow = min(row0 + wid * 16 + m16, NN - 1);
    float bb = b2[0];

    for (int l = 0; l < 3; l++) {
        const __bf16* A = stbf + (size_t)l * NF;
        f32x4 acc[8];
#pragma unroll
        for (int ct = 0; ct < 8; ct++) acc[ct] = (f32x4){0.f, 0.f, 0.f, 0.f};
#pragma unroll
        for (int kk = 0; kk < 4; kk++) {
            bf16x8 a = *(const bf16x8*)&A[(size_t)arow * D + kk * 32 + q * 8];
#pragma unroll
            for (int ct = 0; ct < 8; ct++) {
                bf16x8 b = *(const bf16x8*)&Wl[(ct * 16 + m16) * WS + kk * 32 + q * 8];
                acc[ct] = __builtin_amdgcn_mfma_f32_16x16x32_bf16(a, b, acc[ct], 0, 0, 0);
            }
        }
        float p[4] = {0.f, 0.f, 0.f, 0.f};
#pragma unroll
        for (int ct = 0; ct < 8; ct++) {
            float bv = b1[ct * 16 + m16];
            float wv = w2[ct * 16 + m16];
#pragma unroll
            for (int r = 0; r < 4; r++) p[r] += fmaxf(acc[ct][r] + bv, 0.f) * wv;
        }
#pragma unroll
        for (int r = 0; r < 4; r++) {
#pragma unroll
            for (int off = 1; off < 16; off <<= 1) p[r] += __shfl_xor(p[r], off);
            if (m16 == 0) sc_l[l][wid * 16 + q * 4 + r] = p[r] + bb;
        }
    }
    __syncthreads();

    if (t < 64) {   // per-row softmax over layers
        int row = row0 + t;
        float s0 = sc_l[0][t], s1 = sc_l[1][t], s2 = sc_l[2][t];
        float m = fmaxf(s0, fmaxf(s1, s2));
        float e0 = expf(s0 - m), e1 = expf(s1 - m), e2 = expf(s2 - m);
        float inv = 1.f / (e0 + e1 + e2);
        lw_l[0][t] = e0 * inv;
        lw_l[1][t] = e1 * inv;
        lw_l[2][t] = e2 * inv;
        if (row < NN) {
            lw_out[row] = e0 * inv;
            lw_out[NN + row] = e1 * inv;
            lw_out[2 * NN + row] = e2 * inv;
        }
    }
    __syncthreads();

    // weighted sum over f32 stacked (64 rows x 32 float4)
    for (int i = t; i < 64 * 32; i += 256) {
        int r = i >> 5, c4 = i & 31;
        int row = row0 + r;
        if (row >= NN) break;
        float4 v0 = ((const float4*)(st + (size_t)row * D))[c4];
        float4 v1 = ((const float4*)(st + (size_t)NF + (size_t)row * D))[c4];
        float4 v2 = ((const float4*)(st + 2 * (size_t)NF + (size_t)row * D))[c4];
        float w0 = lw_l[0][r], w1 = lw_l[1][r], w2v = lw_l[2][r];
        float4 o;
        o.x = w0 * v0.x + w1 * v1.x + w2v * v2.x;
        o.y = w0 * v0.y + w1 * v1.y + w2v * v2.y;
        o.z = w0 * v0.z + w1 * v1.z + w2v * v2.z;
        o.w = w0 * v0.w + w1 * v1.w + w2v * v2.w;
        ((float4*)(out + (size_t)row * D))[c4] = o;
    }
}

extern "C" void kernel_launch(void* const* d_in, const int* in_sizes, int n_in,
                              void* d_out, int out_size, void* d_ws, size_t ws_size,
                              hipStream_t stream) {
    const float* x = (const float*)d_in[0];
    const int* ei = (const int*)d_in[1];
    const float* conf = (const float*)d_in[2];
    const float* msg_W1 = (const float*)d_in[3];
    const float* msg_b1 = (const float*)d_in[4];
    const float* msg_W2 = (const float*)d_in[5];
    const float* msg_b2 = (const float*)d_in[6];
    const float* self_W1 = (const float*)d_in[7];
    const float* self_b1 = (const float*)d_in[8];
    const float* self_W2 = (const float*)d_in[9];
    const float* self_b2 = (const float*)d_in[10];
    const float* score_W1 = (const float*)d_in[11];
    const float* score_b1 = (const float*)d_in[12];
    const float* score_W2 = (const float*)d_in[13];
    const float* score_b2 = (const float*)d_in[14];

    float* out = (float*)d_out;                 // [NN,D]
    float* out_stacked = out + NF;              // [3,NN,D]  (canonical f32, graded)
    float* out_lw = out + 4 * (size_t)NF;       // [3,NN]

    float* w = (float*)d_ws;
    float* Mself = w;                              // NF f32
    float2* meta = (float2*)(w + (size_t)NF);      // NE x {src, weight}
    __bf16* xbf = (__bf16*)(meta + NE);            // NF bf16
    __bf16* stbf = xbf + (size_t)NF;               // 3*NF bf16 (per-layer stacked)
    __bf16* Mbf = stbf + 3 * (size_t)NF;           // NF bf16 (msg MLP out, gather set)
    __bf16* wt = Mbf + (size_t)NF;                 // 13 * D * WS bf16
    int* local_rank = (int*)(wt + 13 * (size_t)D * WS);  // NE
    int* cnt_blk = local_rank + NE;                // NBLK * NN
    int* row_ptr = cnt_blk + NBLK * NN;            // NN+1
    int* cnt = row_ptr + NN + 1;                   // NN

    const size_t MAT = (size_t)D * WS;
    const int GE = (NE + 255) / 256;  // 2500
    const int GB32 = (NN + 31) / 32;  // 313
    const int GB64 = (NN + 63) / 64;  // 157

    hist_lds_kernel<<<NBLK, 256, 0, stream>>>(ei, cnt_blk, local_rank);
    prep_all_kernel<<<2513, 256, 0, stream>>>((const float2*)x, (bf16x2*)xbf,
                                              msg_W1, msg_W2, self_W1, self_W2, score_W1, wt);
    colsum_kernel<<<(NN + 255) / 256, 256, 0, stream>>>(cnt_blk, cnt);
    scan_kernel<<<1, 256, 0, stream>>>(cnt, row_ptr);
    scatter_kernel<<<GE, 256, 0, stream>>>(ei, conf, local_rank, cnt_blk, row_ptr, meta);

    for (int l = 0; l < 3; l++) {
        const __bf16* a_in = (l == 0) ? xbf : stbf + (size_t)(l - 1) * NF;
        mlp_pair_mfma<<<dim3(GB32, 2), 128, 0, stream>>>(
            a_in,
            wt + (size_t)l * MAT, msg_b1 + (size_t)l * D,
            wt + (size_t)(3 + l) * MAT, msg_b2 + (size_t)l * D, Mbf,
            wt + (size_t)(6 + l) * MAT, self_b1 + (size_t)l * D,
            wt + (size_t)(9 + l) * MAT, self_b2 + (size_t)l * D, Mself);
        aggregate_kernel<<<NN / 4, 256, 0, stream>>>(
            (const uint4*)Mbf, (const float4*)Mself, row_ptr, meta,
            (float4*)(out_stacked + (size_t)l * NF),
            (bf16x8*)(stbf + (size_t)l * NF));
    }

    score_finalize_mfma<<<GB64, 256, 0, stream>>>(
        stbf, out_stacked, wt + 12 * MAT, score_b1, score_W2, score_b2, out, out_lw);
}

// Round 11
// 254.155 us; speedup vs baseline: 2.2999x; 1.1208x over previous
//
#include <hip/hip_runtime.h>

#define NN 10000
#define NE 640000
#define D 128
#define NF (NN * D)
#define WS 136   // padded bf16 row stride: 272 B = 16B-aligned, 2-way-free LDS banks
#define WBYTES (D * WS * 2)      // 34816 B per W^T matrix
#define WCHUNKS (WBYTES / 1024)  // 34 async 1KB wave-chunks
#define NBLK 100                 // hist blocks
#define EPB (NE / NBLK)          // 6400 edges per hist block
#define MPAD 1000000             // padded meta capacity: 640k + 10k*31 + slack

typedef __bf16 bf16x8 __attribute__((ext_vector_type(8)));
typedef __bf16 bf16x2 __attribute__((ext_vector_type(2)));
typedef float f32x4 __attribute__((ext_vector_type(4)));

// async global->LDS, 16B per lane, 1 KB per wave-call [m97-verified width=16]
__device__ __forceinline__ void async_copy16(const void* g, void* l) {
    __builtin_amdgcn_global_load_lds(
        (const __attribute__((address_space(1))) unsigned int*)g,
        (__attribute__((address_space(3))) unsigned int*)l, 16, 0, 0);
}

// ---------------- fused: LDS histogram | x->bf16 | W->bf16 transposed ----------------
// blocks [0,100): per-block LDS histogram + local rank (no global atomics)
// blocks [100,2600): x -> bf16 ;  blocks [2600,2613): W -> Wt[n][k]

__global__ __launch_bounds__(256) void hist_prep_kernel(
    const int* __restrict__ ei, int* __restrict__ cnt_blk, int* __restrict__ local_rank,
    const float2* __restrict__ x2, bf16x2* __restrict__ xbf,
    const float* __restrict__ mW1, const float* __restrict__ mW2,
    const float* __restrict__ sW1, const float* __restrict__ sW2,
    const float* __restrict__ scW1, __bf16* __restrict__ wt) {
    __shared__ int hist[NN];   // 40 KB (allocated for all blocks; prep is streaming)
    int b = blockIdx.x, t = threadIdx.x;
    if (b < NBLK) {
        for (int i = t; i < NN; i += 256) hist[i] = 0;
        __syncthreads();
        int base = b * EPB;
#pragma unroll 1
        for (int i = 0; i < EPB / 256; i++) {
            int e = base + i * 256 + t;
            local_rank[e] = atomicAdd(&hist[ei[NE + e]], 1);
        }
        __syncthreads();
        for (int i = t; i < NN; i += 256) cnt_blk[b * NN + i] = hist[i];
    } else if (b < 2600) {
        int i = (b - NBLK) * 256 + t;   // NF/2 = 640000
        float2 v = x2[i];
        bf16x2 o;
        o.x = (__bf16)v.x;
        o.y = (__bf16)v.y;
        xbf[i] = o;
    } else {
        int m = b - 2600;  // 0-2 msg_W1, 3-5 msg_W2, 6-8 self_W1, 9-11 self_W2, 12 score_W1
        const float* W = (m < 3)   ? mW1 + (size_t)m * D * D
                       : (m < 6)   ? mW2 + (size_t)(m - 3) * D * D
                       : (m < 9)   ? sW1 + (size_t)(m - 6) * D * D
                       : (m < 12)  ? sW2 + (size_t)(m - 9) * D * D
                                   : scW1;
        __bf16* o = wt + (size_t)m * D * WS;
        for (int i = t; i < D * D; i += 256) {
            int k = i >> 7, n = i & 127;
            o[n * WS + k] = (__bf16)W[i];
        }
    }
}

// per-node prefix over blocks (in place) + total count; fully coalesced
__global__ void colsum_kernel(int* __restrict__ cnt_blk, int* __restrict__ cnt) {
    int n = blockIdx.x * 256 + threadIdx.x;
    if (n >= NN) return;
    int acc = 0;
#pragma unroll 4
    for (int b = 0; b < NBLK; b++) {
        int v = cnt_blk[b * NN + n];
        cnt_blk[b * NN + n] = acc;
        acc += v;
    }
    cnt[n] = acc;
}

// scan over PADDED counts (each row rounded up to 32) -> guard-free aggregate
__global__ void scan_kernel(const int* __restrict__ cnt, int* __restrict__ row_ptr) {
    __shared__ int lds[256];
    int t = threadIdx.x;
    const int CH = (NN + 255) / 256;  // 40
    int base = t * CH;
    int s = 0;
    for (int i = 0; i < CH; i++) {
        int idx = base + i;
        if (idx < NN) s += (cnt[idx] + 31) & ~31;
    }
    lds[t] = s;
    __syncthreads();
    for (int off = 1; off < 256; off <<= 1) {
        int v = (t >= off) ? lds[t - off] : 0;
        __syncthreads();
        lds[t] += v;
        __syncthreads();
    }
    int run = (t == 0) ? 0 : lds[t - 1];
    for (int i = 0; i < CH; i++) {
        int idx = base + i;
        if (idx < NN) {
            row_ptr[idx] = run;
            run += (cnt[idx] + 31) & ~31;
        }
    }
    if (t == 255) row_ptr[NN] = lds[255];
}

// atomic-free scatter into the padded CSR (pad slots pre-zeroed by memset)
__global__ void scatter_kernel(const int* __restrict__ ei, const float* __restrict__ conf,
                               const int* __restrict__ local_rank,
                               const int* __restrict__ cnt_blk,
                               const int* __restrict__ row_ptr, float2* __restrict__ meta) {
    int e = blockIdx.x * 256 + threadIdx.x;
    if (e >= NE) return;
    int s = ei[e];
    int d = ei[NE + e];
    int blk = e / EPB;
    int pos = row_ptr[d] + cnt_blk[blk * NN + d] + local_rank[e];
    meta[pos] = make_float2(__int_as_float(s), expf(-fabsf(conf[s] - conf[d])));
}

// ---------------- fused 2-layer MLP via bf16 MFMA ----------------

__global__ __launch_bounds__(128) void mlp_pair_mfma(
    const __bf16* __restrict__ Abf,
    const __bf16* __restrict__ Wt1a, const float* __restrict__ b1a,
    const __bf16* __restrict__ Wt2a, const float* __restrict__ b2a, __bf16* __restrict__ Mbf,
    const __bf16* __restrict__ Wt1b, const float* __restrict__ b1b,
    const __bf16* __restrict__ Wt2b, const float* __restrict__ b2b, float* __restrict__ Cself) {
    const __bf16* Wt1 = blockIdx.y ? Wt1b : Wt1a;
    const float* b1 = blockIdx.y ? b1b : b1a;
    const __bf16* Wt2 = blockIdx.y ? Wt2b : Wt2a;
    const float* b2 = blockIdx.y ? b2b : b2a;

    __shared__ __align__(16) __bf16 Wl[2][D * WS];    // 2 x 34816 B
    __shared__ __align__(16) __bf16 Tl[2][16 * WS];   // 4352 B per wave
    int t = threadIdx.x;
    int wid = t >> 6, lane = t & 63;
    int m16 = lane & 15, q = lane >> 4;

    for (int c = wid; c < WCHUNKS; c += 2)
        async_copy16((const char*)Wt1 + c * 1024 + lane * 16,
                     (char*)&Wl[0][0] + c * 1024 + lane * 16);

    int row0 = blockIdx.x * 32 + wid * 16;
    int arow = min(row0 + m16, NN - 1);

    bf16x8 af[4];
#pragma unroll
    for (int kk = 0; kk < 4; kk++) af[kk] = *(const bf16x8*)&Abf[(size_t)arow * D + kk * 32 + q * 8];
    float b1v[8], b2v[8];
#pragma unroll
    for (int ct = 0; ct < 8; ct++) { b1v[ct] = b1[ct * 16 + m16]; b2v[ct] = b2[ct * 16 + m16]; }

    __syncthreads();   // drains W1 staging

    for (int c = wid; c < WCHUNKS; c += 2)   // W2 staging overlaps stage-1 MFMAs
        async_copy16((const char*)Wt2 + c * 1024 + lane * 16,
                     (char*)&Wl[1][0] + c * 1024 + lane * 16);

    f32x4 acc[8];
#pragma unroll
    for (int ct = 0; ct < 8; ct++) acc[ct] = (f32x4){0.f, 0.f, 0.f, 0.f};
#pragma unroll
    for (int kk = 0; kk < 4; kk++) {
#pragma unroll
        for (int ct = 0; ct < 8; ct++) {
            bf16x8 b = *(const bf16x8*)&Wl[0][(ct * 16 + m16) * WS + kk * 32 + q * 8];
            acc[ct] = __builtin_amdgcn_mfma_f32_16x16x32_bf16(af[kk], b, acc[ct], 0, 0, 0);
        }
    }
#pragma unroll
    for (int ct = 0; ct < 8; ct++) {
#pragma unroll
        for (int r = 0; r < 4; r++) {
            float v = fmaxf(acc[ct][r] + b1v[ct], 0.f);
            Tl[wid][(q * 4 + r) * WS + ct * 16 + m16] = (__bf16)v;
        }
    }
    __syncthreads();   // drains W2 staging; T is wave-private

#pragma unroll
    for (int ct = 0; ct < 8; ct++) acc[ct] = (f32x4){0.f, 0.f, 0.f, 0.f};
#pragma unroll
    for (int kk = 0; kk < 4; kk++) {
        bf16x8 a = *(const bf16x8*)&Tl[wid][m16 * WS + kk * 32 + q * 8];
#pragma unroll
        for (int ct = 0; ct < 8; ct++) {
            bf16x8 b = *(const bf16x8*)&Wl[1][(ct * 16 + m16) * WS + kk * 32 + q * 8];
            acc[ct] = __builtin_amdgcn_mfma_f32_16x16x32_bf16(a, b, acc[ct], 0, 0, 0);
        }
    }
    if (blockIdx.y == 0) {
#pragma unroll
        for (int ct = 0; ct < 8; ct++) {
#pragma unroll
            for (int r = 0; r < 4; r++) {
                int row = row0 + q * 4 + r;
                if (row < NN) Mbf[(size_t)row * D + ct * 16 + m16] = (__bf16)(acc[ct][r] + b2v[ct]);
            }
        }
    } else {
#pragma unroll
        for (int ct = 0; ct < 8; ct++) {
#pragma unroll
            for (int r = 0; r < 4; r++) {
                int row = row0 + q * 4 + r;
                if (row < NN) Cself[(size_t)row * D + ct * 16 + m16] = acc[ct][r] + b2v[ct];
            }
        }
    }
}

// ---------------- CSR aggregate: padded rows, shuffle-broadcast meta ----------------
// Rows are multiples of 32 (pad: src=0, w=0 -> L2-hot no-op gathers). Per chunk:
// ONE meta vector load (lanes 0..31 hold 32 edges), next chunk software-pipelined;
// src/w broadcast via shfl; 8 straight-line uint4 gathers (4 edges each, 1 KB/instr).

__global__ __launch_bounds__(256) void aggregate_kernel(
    const uint4* __restrict__ Mbf4, const float4* __restrict__ Mself4,
    const int* __restrict__ row_ptr, const float2* __restrict__ meta,
    float4* __restrict__ out4, bf16x8* __restrict__ stbf8) {
    int wid = (blockIdx.x * 256 + threadIdx.x) >> 6;   // node id (2500*4 = NN)
    int lane = threadIdx.x & 63;
    int q = lane >> 4, l4 = lane & 15, l5 = lane & 31;
    int beg = row_ptr[wid], end = row_ptr[wid + 1];
    float a[8] = {0.f, 0.f, 0.f, 0.f, 0.f, 0.f, 0.f, 0.f};
    float2 mcur = meta[beg + l5];            // chunk 0 meta (slack-safe)
    for (int j = beg; j < end; j += 32) {
        float2 mnext = meta[j + 32 + l5];    // prefetch next chunk (slack-safe)
        int srcid[8];
        float wgt[8];
#pragma unroll
        for (int u = 0; u < 8; u++) {
            int sl = 4 * u + q;
            srcid[u] = __float_as_int(__shfl(mcur.x, sl));
            wgt[u] = __shfl(mcur.y, sl);
        }
        uint4 g[8];
#pragma unroll
        for (int u = 0; u < 8; u++) g[u] = Mbf4[(size_t)srcid[u] * 16 + l4];
#pragma unroll
        for (int u = 0; u < 8; u++) {
            float w = wgt[u];
            a[0] = fmaf(w, __uint_as_float(g[u].x << 16), a[0]);
            a[1] = fmaf(w, __uint_as_float(g[u].x & 0xFFFF0000u), a[1]);
            a[2] = fmaf(w, __uint_as_float(g[u].y << 16), a[2]);
            a[3] = fmaf(w, __uint_as_float(g[u].y & 0xFFFF0000u), a[3]);
            a[4] = fmaf(w, __uint_as_float(g[u].z << 16), a[4]);
            a[5] = fmaf(w, __uint_as_float(g[u].z & 0xFFFF0000u), a[5]);
            a[6] = fmaf(w, __uint_as_float(g[u].w << 16), a[6]);
            a[7] = fmaf(w, __uint_as_float(g[u].w & 0xFFFF0000u), a[7]);
        }
        mcur = mnext;
    }
#pragma unroll
    for (int i = 0; i < 8; i++) {
        a[i] += __shfl_xor(a[i], 16);
        a[i] += __shfl_xor(a[i], 32);
    }
    if (q == 0) {   // lanes 0..15: features 8*l4 .. 8*l4+7, canonical
        float4 sv0 = Mself4[(size_t)wid * 32 + 2 * l4];
        float4 sv1 = Mself4[(size_t)wid * 32 + 2 * l4 + 1];
        float4 r0, r1;
        r0.x = fmaxf(a[0] + sv0.x, 0.f);
        r0.y = fmaxf(a[1] + sv0.y, 0.f);
        r0.z = fmaxf(a[2] + sv0.z, 0.f);
        r0.w = fmaxf(a[3] + sv0.w, 0.f);
        r1.x = fmaxf(a[4] + sv1.x, 0.f);
        r1.y = fmaxf(a[5] + sv1.y, 0.f);
        r1.z = fmaxf(a[6] + sv1.z, 0.f);
        r1.w = fmaxf(a[7] + sv1.w, 0.f);
        out4[(size_t)wid * 32 + 2 * l4] = r0;
        out4[(size_t)wid * 32 + 2 * l4 + 1] = r1;
        bf16x8 hb;
        hb[0] = (__bf16)r0.x; hb[1] = (__bf16)r0.y;
        hb[2] = (__bf16)r0.z; hb[3] = (__bf16)r0.w;
        hb[4] = (__bf16)r1.x; hb[5] = (__bf16)r1.y;
        hb[6] = (__bf16)r1.z; hb[7] = (__bf16)r1.w;
        stbf8[(size_t)wid * 16 + l4] = hb;
    }
}

// ---------------- fused scoring (MFMA) + softmax + weighted sum ----------------

__global__ __launch_bounds__(256) void score_finalize_mfma(
    const __bf16* __restrict__ stbf, const float* __restrict__ st,
    const __bf16* __restrict__ Wt1, const float* __restrict__ b1,
    const float* __restrict__ w2, const float* __restrict__ b2,
    float* __restrict__ out, float* __restrict__ lw_out) {
    __shared__ __align__(16) __bf16 Wl[D * WS];   // 34816 B
    __shared__ float sc_l[3][64];
    __shared__ float lw_l[3][64];
    int t = threadIdx.x;
    int wid = t >> 6, lane = t & 63;
    int m16 = lane & 15, q = lane >> 4;
    int row0 = blockIdx.x * 64;

    for (int c = wid; c < WCHUNKS; c += 4)
        async_copy16((const char*)Wt1 + c * 1024 + lane * 16,
                     (char*)&Wl[0] + c * 1024 + lane * 16);
    __syncthreads();

    int arow = min(row0 + wid * 16 + m16, NN - 1);
    float bb = b2[0];

    for (int l = 0; l < 3; l++) {
        const __bf16* A = stbf + (size_t)l * NF;
        f32x4 acc[8];
#pragma unroll
        for (int ct = 0; ct < 8; ct++) acc[ct] = (f32x4){0.f, 0.f, 0.f, 0.f};
#pragma unroll
        for (int kk = 0; kk < 4; kk++) {
            bf16x8 a = *(const bf16x8*)&A[(size_t)arow * D + kk * 32 + q * 8];
#pragma unroll
            for (int ct = 0; ct < 8; ct++) {
                bf16x8 b = *(const bf16x8*)&Wl[(ct * 16 + m16) * WS + kk * 32 + q * 8];
                acc[ct] = __builtin_amdgcn_mfma_f32_16x16x32_bf16(a, b, acc[ct], 0, 0, 0);
            }
        }
        float p[4] = {0.f, 0.f, 0.f, 0.f};
#pragma unroll
        for (int ct = 0; ct < 8; ct++) {
            float bv = b1[ct * 16 + m16];
            float wv = w2[ct * 16 + m16];
#pragma unroll
            for (int r = 0; r < 4; r++) p[r] += fmaxf(acc[ct][r] + bv, 0.f) * wv;
        }
#pragma unroll
        for (int r = 0; r < 4; r++) {
#pragma unroll
            for (int off = 1; off < 16; off <<= 1) p[r] += __shfl_xor(p[r], off);
            if (m16 == 0) sc_l[l][wid * 16 + q * 4 + r] = p[r] + bb;
        }
    }
    __syncthreads();

    if (t < 64) {
        int row = row0 + t;
        float s0 = sc_l[0][t], s1 = sc_l[1][t], s2 = sc_l[2][t];
        float m = fmaxf(s0, fmaxf(s1, s2));
        float e0 = expf(s0 - m), e1 = expf(s1 - m), e2 = expf(s2 - m);
        float inv = 1.f / (e0 + e1 + e2);
        lw_l[0][t] = e0 * inv;
        lw_l[1][t] = e1 * inv;
        lw_l[2][t] = e2 * inv;
        if (row < NN) {
            lw_out[row] = e0 * inv;
            lw_out[NN + row] = e1 * inv;
            lw_out[2 * NN + row] = e2 * inv;
        }
    }
    __syncthreads();

    for (int i = t; i < 64 * 32; i += 256) {
        int r = i >> 5, c4 = i & 31;
        int row = row0 + r;
        if (row >= NN) break;
        float4 v0 = ((const float4*)(st + (size_t)row * D))[c4];
        float4 v1 = ((const float4*)(st + (size_t)NF + (size_t)row * D))[c4];
        float4 v2 = ((const float4*)(st + 2 * (size_t)NF + (size_t)row * D))[c4];
        float w0 = lw_l[0][r], w1 = lw_l[1][r], w2v = lw_l[2][r];
        float4 o;
        o.x = w0 * v0.x + w1 * v1.x + w2v * v2.x;
        o.y = w0 * v0.y + w1 * v1.y + w2v * v2.y;
        o.z = w0 * v0.z + w1 * v1.z + w2v * v2.z;
        o.w = w0 * v0.w + w1 * v1.w + w2v * v2.w;
        ((float4*)(out + (size_t)row * D))[c4] = o;
    }
}

extern "C" void kernel_launch(void* const* d_in, const int* in_sizes, int n_in,
                              void* d_out, int out_size, void* d_ws, size_t ws_size,
                              hipStream_t stream) {
    const float* x = (const float*)d_in[0];
    const int* ei = (const int*)d_in[1];
    const float* conf = (const float*)d_in[2];
    const float* msg_W1 = (const float*)d_in[3];
    const float* msg_b1 = (const float*)d_in[4];
    const float* msg_W2 = (const float*)d_in[5];
    const float* msg_b2 = (const float*)d_in[6];
    const float* self_W1 = (const float*)d_in[7];
    const float* self_b1 = (const float*)d_in[8];
    const float* self_W2 = (const float*)d_in[9];
    const float* self_b2 = (const float*)d_in[10];
    const float* score_W1 = (const float*)d_in[11];
    const float* score_b1 = (const float*)d_in[12];
    const float* score_W2 = (const float*)d_in[13];
    const float* score_b2 = (const float*)d_in[14];

    float* out = (float*)d_out;                 // [NN,D]
    float* out_stacked = out + NF;              // [3,NN,D]  (canonical f32, graded)
    float* out_lw = out + 4 * (size_t)NF;       // [3,NN]

    float* w = (float*)d_ws;
    float* Mself = w;                              // NF f32
    float2* meta = (float2*)(w + (size_t)NF);      // MPAD x {src, weight} (padded CSR)
    __bf16* xbf = (__bf16*)(meta + MPAD);          // NF bf16
    __bf16* stbf = xbf + (size_t)NF;               // 3*NF bf16 (per-layer stacked)
    __bf16* Mbf = stbf + 3 * (size_t)NF;           // NF bf16 (msg MLP out, gather set)
    __bf16* wt = Mbf + (size_t)NF;                 // 13 * D * WS bf16
    int* local_rank = (int*)(wt + 13 * (size_t)D * WS);  // NE
    int* cnt_blk = local_rank + NE;                // NBLK * NN
    int* row_ptr = cnt_blk + NBLK * NN;            // NN+1
    int* cnt = row_ptr + NN + 1;                   // NN

    const size_t MAT = (size_t)D * WS;
    const int GE = (NE + 255) / 256;  // 2500
    const int GB32 = (NN + 31) / 32;  // 313
    const int GB64 = (NN + 63) / 64;  // 157

    hipMemsetAsync(meta, 0, (size_t)MPAD * sizeof(float2), stream);  // zero pad slots
    hist_prep_kernel<<<2613, 256, 0, stream>>>(ei, cnt_blk, local_rank,
                                               (const float2*)x, (bf16x2*)xbf,
                                               msg_W1, msg_W2, self_W1, self_W2, score_W1, wt);
    colsum_kernel<<<(NN + 255) / 256, 256, 0, stream>>>(cnt_blk, cnt);
    scan_kernel<<<1, 256, 0, stream>>>(cnt, row_ptr);
    scatter_kernel<<<GE, 256, 0, stream>>>(ei, conf, local_rank, cnt_blk, row_ptr, meta);

    for (int l = 0; l < 3; l++) {
        const __bf16* a_in = (l == 0) ? xbf : stbf + (size_t)(l - 1) * NF;
        mlp_pair_mfma<<<dim3(GB32, 2), 128, 0, stream>>>(
            a_in,
            wt + (size_t)l * MAT, msg_b1 + (size_t)l * D,
            wt + (size_t)(3 + l) * MAT, msg_b2 + (size_t)l * D, Mbf,
            wt + (size_t)(6 + l) * MAT, self_b1 + (size_t)l * D,
            wt + (size_t)(9 + l) * MAT, self_b2 + (size_t)l * D, Mself);
        aggregate_kernel<<<NN / 4, 256, 0, stream>>>(
            (const uint4*)Mbf, (const float4*)Mself, row_ptr, meta,
            (float4*)(out_stacked + (size_t)l * NF),
            (bf16x8*)(stbf + (size_t)l * NF));
    }

    score_finalize_mfma<<<GB64, 256, 0, stream>>>(
        stbf, out_stacked, wt + 12 * MAT, score_b1, score_W2, score_b2, out, out_lw);
}